// Round 2
// baseline (2515.683 us; speedup 1.0000x reference)
//
#include <hip/hip_runtime.h>
#include <cstdint>
#include <cstddef>

// Problem constants
#define BB 16
#define NN 1024
#define HD 256
#define IND 128
#define OUTD 1024
#define MROWS (BB*NN)          // 16384

#define LEAKY(x) ((x) >= 0.0f ? (x) : 0.01f*(x))

// ---------------- wave helpers ----------------
__device__ inline float wave_sum(float v){
  #pragma unroll
  for (int off=32; off; off>>=1) v += __shfl_xor(v, off, 64);
  return v;
}
__device__ inline float wave_max(float v){
  #pragma unroll
  for (int off=32; off; off>>=1) v = fmaxf(v, __shfl_xor(v, off, 64));
  return v;
}

// ---------------- JAX threefry2x32 gumbel noise ----------------
// jax >= 0.4.36: threefry_partitionable defaults to True.
// Per-element counter = 64-bit flat index as (hi, lo) = (0, m);
// 32-bit output = out_x0 ^ out_x1.
__device__ inline float gumbel_noise(unsigned m){
  const unsigned k0 = 0u, k1 = 42u;                 // jax.random.key(42) -> (0,42)
  const unsigned ks2 = k0 ^ k1 ^ 0x1BD11BDAu;
  unsigned x0 = 0u, x1 = m;
  x0 += k0; x1 += k1;
  #define TF_ROUND(r) { x0 += x1; x1 = (x1 << (r)) | (x1 >> (32-(r))); x1 ^= x0; }
  TF_ROUND(13) TF_ROUND(15) TF_ROUND(26) TF_ROUND(6)
  x0 += k1;  x1 += ks2 + 1u;
  TF_ROUND(17) TF_ROUND(29) TF_ROUND(16) TF_ROUND(24)
  x0 += ks2; x1 += k0 + 2u;
  TF_ROUND(13) TF_ROUND(15) TF_ROUND(26) TF_ROUND(6)
  x0 += k0;  x1 += k1 + 3u;
  TF_ROUND(17) TF_ROUND(29) TF_ROUND(16) TF_ROUND(24)
  x0 += k1;  x1 += ks2 + 4u;
  TF_ROUND(13) TF_ROUND(15) TF_ROUND(26) TF_ROUND(6)
  x0 += ks2; x1 += k0 + 5u;
  #undef TF_ROUND
  unsigned bits = x0 ^ x1;
  float u = __uint_as_float((bits >> 9) | 0x3f800000u) - 1.0f;   // [0,1)
  float t = -logf(u + 1e-20f);
  return -logf(t + 1e-20f) * 0.05f;   // NOISE_SCALE
}

// ---------------- row stats of adj ----------------
// dis[b,i] = (sum_j adj + 1)^-0.5 ; rinv = 1/sum_j adj
__global__ __launch_bounds__(256) void row_stats_k(const float* __restrict__ adj,
                                                   float* __restrict__ dis,
                                                   float* __restrict__ rinv){
  int tid = threadIdx.x, wid = tid >> 6, lane = tid & 63;
  int row = blockIdx.x*4 + wid;
  const float4* rp = (const float4*)(adj + (size_t)row*NN);
  float s = 0.f;
  #pragma unroll
  for (int p=0;p<4;p++){ float4 v = rp[lane + p*64]; s += v.x+v.y+v.z+v.w; }
  s = wave_sum(s);
  if (lane==0){
    dis[row]  = 1.0f/sqrtf(s + 1.0f);
    rinv[row] = 1.0f/s;
  }
}

// ---------------- elementwise ----------------
__global__ __launch_bounds__(256) void scale_rows_k(const float* __restrict__ in, int lda,
                                                    const float* __restrict__ sc,
                                                    float* __restrict__ out){
  int gid = blockIdx.x*256 + threadIdx.x;   // float4 id over [16384][64]
  int row = gid >> 6, c = (gid & 63)*4;
  float4 v = *(const float4*)(in + (size_t)row*lda + c);
  float d = sc[row];
  v.x*=d; v.y*=d; v.z*=d; v.w*=d;
  *(float4*)(out + (size_t)row*HD + c) = v;
}

__global__ __launch_bounds__(256) void sub_abs_k(const float* __restrict__ a, int lda,
                                                 const float* __restrict__ bp, int ldb,
                                                 float* __restrict__ out){
  int gid = blockIdx.x*256 + threadIdx.x;
  int row = gid >> 6, c = (gid & 63)*4;
  float4 va = *(const float4*)(a  + (size_t)row*lda + c);
  float4 vb = *(const float4*)(bp + (size_t)row*ldb + c);
  float4 o = make_float4(fabsf(va.x-vb.x), fabsf(va.y-vb.y), fabsf(va.z-vb.z), fabsf(va.w-vb.w));
  *(float4*)(out + (size_t)row*HD + c) = o;
}

// ---------------- batched GEMM: out = epilogue(adj[b] @ Bm[b]) ----------------
// mode 0 (GCN):  out = leaky(dis_i * (acc + Bm[i]))     (Bm is g = dis .* h)
// mode 1 (LAZY): out = 0.5*(Bm[i] + rinv_i * acc)       (Bm is h)
__global__ __launch_bounds__(256) void gemm_nn_k(const float* __restrict__ A,
                                                 const float* __restrict__ Bm,
                                                 const float* __restrict__ rowscale,
                                                 float* __restrict__ out,
                                                 int ldb, int ldo, int mode){
  __shared__ float Als[32][68];
  __shared__ float Bls[32][68];
  int b  = blockIdx.z;
  const float* Ab = A  + (size_t)b*NN*NN;
  const float* Bb = Bm + (size_t)b*NN*ldb;
  int n0 = blockIdx.x*64, i0 = blockIdx.y*64;
  int tid = threadIdx.x;
  int tn = tid & 15, tm = tid >> 4;
  float acc[4][4] = {};
  for (int kc=0; kc<NN; kc+=32){
    #pragma unroll
    for (int it=0; it<2; it++){
      int f = tid + it*256;
      int r = f >> 3, c4 = (f & 7)*4;
      float4 v = *(const float4*)(Ab + (size_t)(i0+r)*NN + kc + c4);
      Als[c4+0][r]=v.x; Als[c4+1][r]=v.y; Als[c4+2][r]=v.z; Als[c4+3][r]=v.w;
    }
    #pragma unroll
    for (int it=0; it<2; it++){
      int f = tid + it*256;
      int k = f >> 4, n4 = (f & 15)*4;
      *(float4*)&Bls[k][n4] = *(const float4*)(Bb + (size_t)(kc+k)*ldb + n0 + n4);
    }
    __syncthreads();
    #pragma unroll
    for (int k=0;k<32;k++){
      float4 a4 = *(const float4*)&Als[k][tm*4];
      float4 b4 = *(const float4*)&Bls[k][tn*4];
      float av[4] = {a4.x,a4.y,a4.z,a4.w};
      float bv[4] = {b4.x,b4.y,b4.z,b4.w};
      #pragma unroll
      for (int r=0;r<4;r++)
        #pragma unroll
        for (int c=0;c<4;c++) acc[r][c] = fmaf(av[r], bv[c], acc[r][c]);
    }
    __syncthreads();
  }
  #pragma unroll
  for (int r=0;r<4;r++){
    int i  = i0 + tm*4 + r;
    int gm = b*NN + i;
    float sc = rowscale[gm];
    float4 ax = *(const float4*)(Bb + (size_t)i*ldb + n0 + tn*4);
    float4 o;
    if (mode == 0){
      o.x = LEAKY(sc*(acc[r][0]+ax.x));
      o.y = LEAKY(sc*(acc[r][1]+ax.y));
      o.z = LEAKY(sc*(acc[r][2]+ax.z));
      o.w = LEAKY(sc*(acc[r][3]+ax.w));
    } else {
      o.x = 0.5f*(ax.x + sc*acc[r][0]);
      o.y = 0.5f*(ax.y + sc*acc[r][1]);
      o.z = 0.5f*(ax.z + sc*acc[r][2]);
      o.w = 0.5f*(ax.w + sc*acc[r][3]);
    }
    *(float4*)(out + (size_t)gm*ldo + n0 + tn*4) = o;
  }
}

// ---------------- linear: out = act(Ain @ W^T + bias) ----------------
// act 0: none, 1: leaky, 2: sinkhorn init (Z0 = (40*tanh(x)+gumbel)/0.1)
__global__ __launch_bounds__(256) void gemm_nt_k(const float* __restrict__ Ain, int lda,
                                                 const float* __restrict__ W,
                                                 const float* __restrict__ bias,
                                                 float* __restrict__ out, int ldo,
                                                 int K, int act){
  __shared__ float Als[32][68];
  __shared__ float Bls[32][68];
  int o0 = blockIdx.x*64, m0 = blockIdx.y*64;
  int tid = threadIdx.x;
  int tn = tid & 15, tm = tid >> 4;
  float acc[4][4] = {};
  for (int kc=0; kc<K; kc+=32){
    #pragma unroll
    for (int it=0; it<2; it++){
      int f = tid + it*256;
      int r = f >> 3, c4 = (f & 7)*4;
      float4 v = *(const float4*)(Ain + (size_t)(m0+r)*lda + kc + c4);
      Als[c4+0][r]=v.x; Als[c4+1][r]=v.y; Als[c4+2][r]=v.z; Als[c4+3][r]=v.w;
    }
    #pragma unroll
    for (int it=0; it<2; it++){
      int f = tid + it*256;
      int o = f >> 3, c4 = (f & 7)*4;
      float4 v = *(const float4*)(W + (size_t)(o0+o)*K + kc + c4);
      Bls[c4+0][o]=v.x; Bls[c4+1][o]=v.y; Bls[c4+2][o]=v.z; Bls[c4+3][o]=v.w;
    }
    __syncthreads();
    #pragma unroll
    for (int k=0;k<32;k++){
      float4 a4 = *(const float4*)&Als[k][tm*4];
      float4 b4 = *(const float4*)&Bls[k][tn*4];
      float av[4] = {a4.x,a4.y,a4.z,a4.w};
      float bv[4] = {b4.x,b4.y,b4.z,b4.w};
      #pragma unroll
      for (int r=0;r<4;r++)
        #pragma unroll
        for (int c=0;c<4;c++) acc[r][c] = fmaf(av[r], bv[c], acc[r][c]);
    }
    __syncthreads();
  }
  float4 bi = *(const float4*)(bias + o0 + tn*4);
  float bvv[4] = {bi.x,bi.y,bi.z,bi.w};
  #pragma unroll
  for (int r=0;r<4;r++){
    int m = m0 + tm*4 + r;
    float vals[4];
    #pragma unroll
    for (int c=0;c<4;c++) vals[c] = acc[r][c] + bvv[c];
    if (act == 1){
      #pragma unroll
      for (int c=0;c<4;c++) vals[c] = LEAKY(vals[c]);
    } else if (act == 2){
      #pragma unroll
      for (int c=0;c<4;c++){
        float lg = 40.0f * tanhf(vals[c]);
        unsigned flat = (unsigned)m*1024u + (unsigned)(o0 + tn*4 + c);
        vals[c] = (lg + gumbel_noise(flat)) / 0.1f;
      }
    }
    float4 o = make_float4(vals[0], vals[1], vals[2], vals[3]);
    *(float4*)(out + (size_t)m*ldo + o0 + tn*4) = o;
  }
}

// ---------------- channel attention + combine ----------------
// e_c = sum_d relu(ch_c[d]) * a2[d]; att = softmax_c(e); h' = 0.25*sum att_c*ch_c
__global__ __launch_bounds__(256) void attn_k(const float* __restrict__ c0,
                                              const float* __restrict__ s0,
                                              const float* __restrict__ s1,
                                              const float* __restrict__ s2,
                                              const float* __restrict__ a2,
                                              float* __restrict__ hp){
  int tid = threadIdx.x, wid = tid >> 6, lane = tid & 63;
  int row = blockIdx.x*4 + wid;
  size_t base = (size_t)row*HD + lane*4;
  float4 av = *(const float4*)(a2 + lane*4);
  float4 v[4];
  v[0] = *(const float4*)(c0 + base);
  v[1] = *(const float4*)(s0 + base);
  v[2] = *(const float4*)(s1 + base);
  v[3] = *(const float4*)(s2 + base);
  float e[4];
  #pragma unroll
  for (int c=0;c<4;c++){
    float p = fmaxf(v[c].x,0.f)*av.x + fmaxf(v[c].y,0.f)*av.y
            + fmaxf(v[c].z,0.f)*av.z + fmaxf(v[c].w,0.f)*av.w;
    e[c] = wave_sum(p);
  }
  float m = fmaxf(fmaxf(e[0],e[1]), fmaxf(e[2],e[3]));
  float w0 = expf(e[0]-m), w1 = expf(e[1]-m), w2 = expf(e[2]-m), w3 = expf(e[3]-m);
  float inv = 0.25f / (w0+w1+w2+w3);
  float4 o;
  o.x = (w0*v[0].x + w1*v[1].x + w2*v[2].x + w3*v[3].x)*inv;
  o.y = (w0*v[0].y + w1*v[1].y + w2*v[2].y + w3*v[3].y)*inv;
  o.z = (w0*v[0].z + w1*v[1].z + w2*v[2].z + w3*v[3].z)*inv;
  o.w = (w0*v[0].w + w1*v[1].w + w2*v[2].w + w3*v[3].w)*inv;
  *(float4*)(hp + base) = o;
}

// ---------------- batched 1024x1024 transpose ----------------
__global__ __launch_bounds__(256) void transpose_k(const float* __restrict__ Z,
                                                   float* __restrict__ Zt){
  __shared__ float tile[64][65];
  int bz = blockIdx.z;
  int i0 = blockIdx.y*64, j0 = blockIdx.x*64;
  const float* Zb = Z  + (size_t)bz*NN*NN;
  float*       Tb = Zt + (size_t)bz*NN*NN;
  int tid = threadIdx.x;
  #pragma unroll
  for (int it=0; it<4; it++){
    int f = tid + it*256;
    int r = f >> 4, c4 = (f & 15)*4;
    float4 v = *(const float4*)(Zb + (size_t)(i0+r)*NN + j0 + c4);
    tile[r][c4+0]=v.x; tile[r][c4+1]=v.y; tile[r][c4+2]=v.z; tile[r][c4+3]=v.w;
  }
  __syncthreads();
  #pragma unroll
  for (int it=0; it<4; it++){
    int f = tid + it*256;
    int r = f >> 4, c4 = (f & 15)*4;
    float4 v = make_float4(tile[c4+0][r], tile[c4+1][r], tile[c4+2][r], tile[c4+3][r]);
    *(float4*)(Tb + (size_t)(j0+r)*NN + i0 + c4) = v;
  }
}

// ---------------- sinkhorn passes ----------------
// out[row] = LSE_pos(Z[row][pos] - sub[b*1024+pos]),  b = row>>10
__global__ __launch_bounds__(256) void lse_rows_k(const float* __restrict__ Z,
                                                  const float* __restrict__ sub,
                                                  float* __restrict__ outv){
  __shared__ float redm[4], reds[4];
  int tid = threadIdx.x, wid = tid >> 6, lane = tid & 63;
  int row = blockIdx.x;
  int b = row >> 10;
  float4 z  = *(const float4*)(Z   + (size_t)row*NN + tid*4);
  float4 s4 = *(const float4*)(sub + (size_t)b*NN   + tid*4);
  float x0 = z.x - s4.x, x1 = z.y - s4.y, x2 = z.z - s4.z, x3 = z.w - s4.w;
  float m = fmaxf(fmaxf(x0,x1), fmaxf(x2,x3));
  m = wave_max(m);
  if (lane==0) redm[wid] = m;
  __syncthreads();
  float M = fmaxf(fmaxf(redm[0],redm[1]), fmaxf(redm[2],redm[3]));
  float s = expf(x0-M) + expf(x1-M) + expf(x2-M) + expf(x3-M);
  s = wave_sum(s);
  if (lane==0) reds[wid] = s;
  __syncthreads();
  if (tid==0) outv[row] = M + logf(reds[0]+reds[1]+reds[2]+reds[3]);
}

// T[row=(b,j)] = sum_i exp(Zt[row][i] - L[b*1024+i] - C[row])
__global__ __launch_bounds__(256) void sumexp_rows_k(const float* __restrict__ Zt,
                                                     const float* __restrict__ Lv,
                                                     const float* __restrict__ Cv,
                                                     float* __restrict__ Tv){
  __shared__ float reds[4];
  int tid = threadIdx.x, wid = tid >> 6, lane = tid & 63;
  int row = blockIdx.x;
  int b = row >> 10;
  float sc = Cv[row];
  float4 z  = *(const float4*)(Zt + (size_t)row*NN + tid*4);
  float4 l4 = *(const float4*)(Lv + (size_t)b*NN   + tid*4);
  float s = expf(z.x - l4.x - sc) + expf(z.y - l4.y - sc)
          + expf(z.z - l4.z - sc) + expf(z.w - l4.w - sc);
  s = wave_sum(s);
  if (lane==0) reds[wid] = s;
  __syncthreads();
  if (tid==0) Tv[row] = reds[0]+reds[1]+reds[2]+reds[3];
}

// P = exp(Z0 - C_j - L_i) / T_j
__global__ __launch_bounds__(256) void writep_k(const float* __restrict__ Z,
                                                const float* __restrict__ Cv,
                                                const float* __restrict__ Lv,
                                                const float* __restrict__ Tv,
                                                float* __restrict__ P){
  int gid = blockIdx.x*256 + threadIdx.x;  // float4 id over 4M
  int row = gid >> 8;
  int j = (gid & 255)*4;
  int b = row >> 10;
  float4 z = ((const float4*)Z)[gid];
  float4 c = *(const float4*)(Cv + (size_t)b*NN + j);
  float4 t = *(const float4*)(Tv + (size_t)b*NN + j);
  float l = Lv[row];
  float4 o;
  o.x = expf(z.x - c.x - l) / t.x;
  o.y = expf(z.y - c.y - l) / t.y;
  o.z = expf(z.z - c.z - l) / t.z;
  o.w = expf(z.w - c.w - l) / t.w;
  ((float4*)P)[gid] = o;
}

// ---------------- host orchestration ----------------
extern "C" void kernel_launch(void* const* d_in, const int* in_sizes, int n_in,
                              void* d_out, int out_size, void* d_ws, size_t ws_size,
                              hipStream_t stream){
  const float* X    = (const float*)d_in[0];
  const float* adj  = (const float*)d_in[1];
  const float* w_in = (const float*)d_in[2];
  const float* b_in = (const float*)d_in[3];
  const float* cw1  = (const float*)d_in[4];
  const float* cb1  = (const float*)d_in[5];
  const float* cw2  = (const float*)d_in[6];
  const float* cb2  = (const float*)d_in[7];
  const float* ca   = (const float*)d_in[8];
  const float* m1w  = (const float*)d_in[9];
  const float* m1b  = (const float*)d_in[10];
  const float* m2w  = (const float*)d_in[11];
  const float* m2b  = (const float*)d_in[12];

  float* outp = (float*)d_out;
  float* Pout = outp;                              // [0,16M) floats
  float* Z0   = outp + (size_t)16*1024*1024;       // [16M,32M)

  // 4M-float scratch slots inside d_out (dead before P/Z0 are produced)
  const size_t SLOT = (size_t)4*1024*1024;
  float* B0 = outp + 0*SLOT;
  float* B1 = outp + 1*SLOT;
  float* B2 = outp + 2*SLOT;
  float* B3 = outp + 3*SLOT;
  float* B4 = outp + 4*SLOT;
  float* B5 = outp + 5*SLOT;
  float* B6 = outp + 6*SLOT;

  float* ws     = (float*)d_ws;
  float* Zt     = ws;                        // 16M floats (sinkhorn phase)
  float* hidden = ws;                        // 12M floats (layers phase, disjoint lifetime)
  float* vec  = ws + (size_t)16*1024*1024;
  float* dis  = vec;
  float* rinv = vec + 16384;
  float* Rv   = vec + 2*16384;
  float* Cv   = vec + 3*16384;
  float* Lv   = vec + 4*16384;
  float* Tv   = vec + 5*16384;

  dim3 blk(256);
  dim3 gEw(4096);                 // elementwise over [16384][256]
  dim3 gNN(4, 16, 16);            // batched adj gemm
  dim3 gRow(MROWS);

  row_stats_k<<<gEw, blk, 0, stream>>>(adj, dis, rinv);

  // input projection: hidden[:, 0:256] = X @ w_in^T + b_in
  gemm_nt_k<<<dim3(4,256), blk, 0, stream>>>(X, IND, w_in, b_in, hidden, 768, IND, 0);

  for (int l=0; l<2; l++){
    const float* h_in = hidden + l*HD;       // ld 768
    const float* w1 = cw1 + (size_t)l*HD*HD;
    const float* b1 = cb1 + (size_t)l*HD;
    const float* w2 = cw2 + (size_t)l*HD*HD;
    const float* b2 = cb2 + (size_t)l*HD;
    const float* a2 = ca  + (size_t)l*2*HD + HD;   // second half (x-part cancels in softmax)

    scale_rows_k<<<gEw, blk, 0, stream>>>(h_in, 768, dis, B1);                   // g
    gemm_nn_k<<<gNN, blk, 0, stream>>>(adj, B1, dis, B2, HD, HD, 0);             // C0 = leaky(A_hat h)
    gemm_nn_k<<<gNN, blk, 0, stream>>>(adj, h_in, rinv, B3, 768, HD, 1);         // t1 = P h
    sub_abs_k<<<gEw, blk, 0, stream>>>(h_in, 768, B3, HD, B4);                   // S0 = |h - t1|
    gemm_nn_k<<<gNN, blk, 0, stream>>>(adj, B3, rinv, B5, HD, HD, 1);            // t2
    sub_abs_k<<<gEw, blk, 0, stream>>>(B3, HD, B5, HD, B6);                      // S1 = |t1 - t2|
    gemm_nn_k<<<gNN, blk, 0, stream>>>(adj, B5, rinv, B1, HD, HD, 1);            // t3
    gemm_nn_k<<<gNN, blk, 0, stream>>>(adj, B1, rinv, B3, HD, HD, 1);            // t4
    sub_abs_k<<<gEw, blk, 0, stream>>>(B5, HD, B3, HD, B0);                      // S2 = |t2 - t4|
    attn_k<<<gEw, blk, 0, stream>>>(B2, B4, B6, B0, a2, B1);                     // h'
    gemm_nt_k<<<dim3(4,256), blk, 0, stream>>>(B1, HD, w1, b1, B3, HD, HD, 1);   // mid
    gemm_nt_k<<<dim3(4,256), blk, 0, stream>>>(B3, HD, w2, b2, hidden + (l+1)*HD, 768, HD, 1);
  }

  // MLP head
  gemm_nt_k<<<dim3(4,256),  blk, 0, stream>>>(hidden, 768, m1w, m1b, B1, HD, 768, 1);
  gemm_nt_k<<<dim3(16,256), blk, 0, stream>>>(B1, HD, m2w, m2b, Z0, OUTD, HD, 2);  // Z0 incl. gumbel

  // Sinkhorn: Z_t = Z0 - R_i - C_j (rank-1 log-space trick; Z0 read-only)
  transpose_k<<<dim3(16,16,16), blk, 0, stream>>>(Z0, Zt);
  hipMemsetAsync(Cv, 0, MROWS*sizeof(float), stream);
  for (int t=0; t<20; t++){
    lse_rows_k<<<gRow, blk, 0, stream>>>(Z0, Cv, Rv);   // R = rowLSE(Z0 - C)
    lse_rows_k<<<gRow, blk, 0, stream>>>(Zt, Rv, Cv);   // C = colLSE(Z0 - R)
  }
  lse_rows_k<<<gRow, blk, 0, stream>>>(Z0, Cv, Lv);       // final row lse
  sumexp_rows_k<<<gRow, blk, 0, stream>>>(Zt, Lv, Cv, Tv);// column sums of P1
  writep_k<<<gRow, blk, 0, stream>>>(Z0, Cv, Lv, Tv, Pout);
}

// Round 3
// 1727.121 us; speedup vs baseline: 1.4566x; 1.4566x over previous
//
#include <hip/hip_runtime.h>
#include <cstdint>
#include <cstddef>

// Problem constants
#define BB 16
#define NN 1024
#define HD 256
#define IND 128
#define OUTD 1024
#define MROWS (BB*NN)          // 16384

#define LEAKY(x) ((x) >= 0.0f ? (x) : 0.01f*(x))

typedef short short8 __attribute__((ext_vector_type(8)));
typedef float f32x4 __attribute__((ext_vector_type(4)));

// ---------------- wave helpers ----------------
__device__ inline float wave_sum(float v){
  #pragma unroll
  for (int off=32; off; off>>=1) v += __shfl_xor(v, off, 64);
  return v;
}
__device__ inline float wave_max(float v){
  #pragma unroll
  for (int off=32; off; off>>=1) v = fmaxf(v, __shfl_xor(v, off, 64));
  return v;
}

// fp32 -> bf16 round-to-nearest-even
__device__ inline unsigned short f2bf(float x){
  unsigned u = __float_as_uint(x);
  unsigned r = (u + 0x7fffu + ((u >> 16) & 1u)) >> 16;
  return (unsigned short)r;
}

// ---------------- JAX threefry2x32 gumbel noise (partitionable) ----------------
__device__ inline float gumbel_noise(unsigned m){
  const unsigned k0 = 0u, k1 = 42u;
  const unsigned ks2 = k0 ^ k1 ^ 0x1BD11BDAu;
  unsigned x0 = 0u, x1 = m;
  x0 += k0; x1 += k1;
  #define TF_ROUND(r) { x0 += x1; x1 = (x1 << (r)) | (x1 >> (32-(r))); x1 ^= x0; }
  TF_ROUND(13) TF_ROUND(15) TF_ROUND(26) TF_ROUND(6)
  x0 += k1;  x1 += ks2 + 1u;
  TF_ROUND(17) TF_ROUND(29) TF_ROUND(16) TF_ROUND(24)
  x0 += ks2; x1 += k0 + 2u;
  TF_ROUND(13) TF_ROUND(15) TF_ROUND(26) TF_ROUND(6)
  x0 += k0;  x1 += k1 + 3u;
  TF_ROUND(17) TF_ROUND(29) TF_ROUND(16) TF_ROUND(24)
  x0 += k1;  x1 += ks2 + 4u;
  TF_ROUND(13) TF_ROUND(15) TF_ROUND(26) TF_ROUND(6)
  x0 += ks2; x1 += k0 + 5u;
  #undef TF_ROUND
  unsigned bits = x0 ^ x1;
  float u = __uint_as_float((bits >> 9) | 0x3f800000u) - 1.0f;   // [0,1)
  float t = -logf(u + 1e-20f);
  return -logf(t + 1e-20f) * 0.05f;   // NOISE_SCALE
}

// ---------------- row stats of adj ----------------
__global__ __launch_bounds__(256) void row_stats_k(const float* __restrict__ adj,
                                                   float* __restrict__ dis,
                                                   float* __restrict__ rinv){
  int tid = threadIdx.x, wid = tid >> 6, lane = tid & 63;
  int row = blockIdx.x*4 + wid;
  const float4* rp = (const float4*)(adj + (size_t)row*NN);
  float s = 0.f;
  #pragma unroll
  for (int p=0;p<4;p++){ float4 v = rp[lane + p*64]; s += v.x+v.y+v.z+v.w; }
  s = wave_sum(s);
  if (lane==0){
    dis[row]  = 1.0f/sqrtf(s + 1.0f);
    rinv[row] = 1.0f/s;
  }
}

// ---------------- converts ----------------
// adj fp32 [16M] -> bf16 [16M]
__global__ __launch_bounds__(256) void adj2bf16_k(const float* __restrict__ adj,
                                                  unsigned short* __restrict__ abf){
  int gid = blockIdx.x*256 + threadIdx.x;
  float4 v = ((const float4*)adj)[gid];
  ushort4 o;
  o.x = f2bf(v.x); o.y = f2bf(v.y); o.z = f2bf(v.z); o.w = f2bf(v.w);
  ((ushort4*)abf)[gid] = o;
}

// fp32 [16][1024 i][ld] (cols c0..255) -> bf16 transposed [16][256 c][1024 i]
__global__ __launch_bounds__(256) void bconv_t_k(const float* __restrict__ in, int ld,
                                                 unsigned short* __restrict__ outT){
  __shared__ float tile[64][68];
  int b  = blockIdx.z;
  int i0 = blockIdx.x*64;      // 16 tiles
  int c0 = blockIdx.y*64;      // 4 tiles
  const float* inb = in + (size_t)b*NN*ld;
  unsigned short* ob = outT + (size_t)b*HD*NN;
  int tid = threadIdx.x;
  #pragma unroll
  for (int it=0; it<4; it++){
    int f = tid + it*256;
    int r = f >> 4, c4 = (f & 15)*4;
    float4 v = *(const float4*)(inb + (size_t)(i0+r)*ld + c0 + c4);
    tile[r][c4+0]=v.x; tile[r][c4+1]=v.y; tile[r][c4+2]=v.z; tile[r][c4+3]=v.w;
  }
  __syncthreads();
  #pragma unroll
  for (int it=0; it<4; it++){
    int f = tid + it*256;
    int cl = f >> 4, r4 = (f & 15)*4;
    ushort4 o;
    o.x = f2bf(tile[r4+0][cl]);
    o.y = f2bf(tile[r4+1][cl]);
    o.z = f2bf(tile[r4+2][cl]);
    o.w = f2bf(tile[r4+3][cl]);
    *(ushort4*)(ob + (size_t)(c0+cl)*NN + i0 + r4) = o;
  }
}

// ---------------- elementwise ----------------
__global__ __launch_bounds__(256) void scale_rows_k(const float* __restrict__ in, int lda,
                                                    const float* __restrict__ sc,
                                                    float* __restrict__ out){
  int gid = blockIdx.x*256 + threadIdx.x;
  int row = gid >> 6, c = (gid & 63)*4;
  float4 v = *(const float4*)(in + (size_t)row*lda + c);
  float d = sc[row];
  v.x*=d; v.y*=d; v.z*=d; v.w*=d;
  *(float4*)(out + (size_t)row*HD + c) = v;
}

__global__ __launch_bounds__(256) void sub_abs_k(const float* __restrict__ a, int lda,
                                                 const float* __restrict__ bp, int ldb,
                                                 float* __restrict__ out){
  int gid = blockIdx.x*256 + threadIdx.x;
  int row = gid >> 6, c = (gid & 63)*4;
  float4 va = *(const float4*)(a  + (size_t)row*lda + c);
  float4 vb = *(const float4*)(bp + (size_t)row*ldb + c);
  float4 o = make_float4(fabsf(va.x-vb.x), fabsf(va.y-vb.y), fabsf(va.z-vb.z), fabsf(va.w-vb.w));
  *(float4*)(out + (size_t)row*HD + c) = o;
}

// ---------------- MFMA batched GEMM: acc = adj[b] @ B[b] ----------------
// A bf16 [16][1024][1024] row-major; Bt bf16 [16][256 n][1024 k] (n-major).
// mode 0: out = leaky(sc_i*(acc + Bsrc[i][n]))   (GCN, Bsrc = g fp32)
// mode 1: out = 0.5*(Bsrc[i][n] + sc_i*acc)      (lazy walk, Bsrc = h fp32)
__global__ __launch_bounds__(512) void gemm_nn_mfma_k(const unsigned short* __restrict__ Abf,
                                                      const unsigned short* __restrict__ Btb,
                                                      const float* __restrict__ Bsrc, int ldb,
                                                      const float* __restrict__ rowscale,
                                                      float* __restrict__ out, int mode){
  __shared__ unsigned short Als[128][40];   // rows i, cols k (padded 32->40)
  __shared__ unsigned short Bls[128][40];   // rows n, cols k
  int b  = blockIdx.z;
  int n0 = blockIdx.x*128;     // 2
  int i0 = blockIdx.y*128;     // 8
  const unsigned short* Ab = Abf + (size_t)b*NN*NN + (size_t)i0*NN;
  const unsigned short* Bb = Btb + (size_t)b*HD*NN + (size_t)n0*NN;
  int tid = threadIdx.x;
  int wave = tid >> 6, lane = tid & 63;
  int quad = lane >> 4, l16 = lane & 15;
  int wr = (wave >> 2)*64;         // 0 or 64
  int wc = (wave & 3)*32;          // 0,32,64,96

  f32x4 acc[4][2] = {};            // [rowtile][coltile]

  int sr = tid >> 2, sg = tid & 3; // staging: 512 segs of 8 bf16
  for (int kc = 0; kc < NN; kc += 32){
    short8 av = *(const short8*)(Ab + (size_t)sr*NN + kc + sg*8);
    short8 bv = *(const short8*)(Bb + (size_t)sr*NN + kc + sg*8);
    *(short8*)&Als[sr][sg*8] = av;
    *(short8*)&Bls[sr][sg*8] = bv;
    __syncthreads();
    short8 af[4];
    #pragma unroll
    for (int rt=0; rt<4; rt++)
      af[rt] = *(const short8*)&Als[wr + rt*16 + l16][quad*8];
    #pragma unroll
    for (int ct=0; ct<2; ct++){
      short8 bfr = *(const short8*)&Bls[wc + ct*16 + l16][quad*8];
      #pragma unroll
      for (int rt=0; rt<4; rt++)
        acc[rt][ct] = __builtin_amdgcn_mfma_f32_16x16x32_bf16(af[rt], bfr, acc[rt][ct], 0, 0, 0);
    }
    __syncthreads();
  }

  #pragma unroll
  for (int rt=0; rt<4; rt++){
    #pragma unroll
    for (int p=0; p<4; p++){
      int gr = i0 + wr + rt*16 + quad*4 + p;
      int gm = b*NN + gr;
      float sc = rowscale[gm];
      #pragma unroll
      for (int ct=0; ct<2; ct++){
        int gc = n0 + wc + ct*16 + l16;
        float a = acc[rt][ct][p];
        float src = Bsrc[(size_t)gm*ldb + gc];
        float o = (mode == 0) ? LEAKY(sc*(a + src)) : 0.5f*(src + sc*a);
        out[(size_t)gm*HD + gc] = o;
      }
    }
  }
}

// ---------------- linear: out = act(Ain @ W^T + bias) (fp32 vector) ----------------
// act 0: none, 1: leaky, 2: sinkhorn init (Z0 = (40*tanh(x)+gumbel)/0.1)
__global__ __launch_bounds__(256) void gemm_nt_k(const float* __restrict__ Ain, int lda,
                                                 const float* __restrict__ W,
                                                 const float* __restrict__ bias,
                                                 float* __restrict__ out, int ldo,
                                                 int K, int act){
  __shared__ float Als[32][68];
  __shared__ float Bls[32][68];
  int o0 = blockIdx.x*64, m0 = blockIdx.y*64;
  int tid = threadIdx.x;
  int tn = tid & 15, tm = tid >> 4;
  float acc[4][4] = {};
  for (int kc=0; kc<K; kc+=32){
    #pragma unroll
    for (int it=0; it<2; it++){
      int f = tid + it*256;
      int r = f >> 3, c4 = (f & 7)*4;
      float4 v = *(const float4*)(Ain + (size_t)(m0+r)*lda + kc + c4);
      Als[c4+0][r]=v.x; Als[c4+1][r]=v.y; Als[c4+2][r]=v.z; Als[c4+3][r]=v.w;
    }
    #pragma unroll
    for (int it=0; it<2; it++){
      int f = tid + it*256;
      int o = f >> 3, c4 = (f & 7)*4;
      float4 v = *(const float4*)(W + (size_t)(o0+o)*K + kc + c4);
      Bls[c4+0][o]=v.x; Bls[c4+1][o]=v.y; Bls[c4+2][o]=v.z; Bls[c4+3][o]=v.w;
    }
    __syncthreads();
    #pragma unroll
    for (int k=0;k<32;k++){
      float4 a4 = *(const float4*)&Als[k][tm*4];
      float4 b4 = *(const float4*)&Bls[k][tn*4];
      float av[4] = {a4.x,a4.y,a4.z,a4.w};
      float bv[4] = {b4.x,b4.y,b4.z,b4.w};
      #pragma unroll
      for (int r=0;r<4;r++)
        #pragma unroll
        for (int c=0;c<4;c++) acc[r][c] = fmaf(av[r], bv[c], acc[r][c]);
    }
    __syncthreads();
  }
  float4 bi = *(const float4*)(bias + o0 + tn*4);
  float bvv[4] = {bi.x,bi.y,bi.z,bi.w};
  #pragma unroll
  for (int r=0;r<4;r++){
    int m = m0 + tm*4 + r;
    float vals[4];
    #pragma unroll
    for (int c=0;c<4;c++) vals[c] = acc[r][c] + bvv[c];
    if (act == 1){
      #pragma unroll
      for (int c=0;c<4;c++) vals[c] = LEAKY(vals[c]);
    } else if (act == 2){
      #pragma unroll
      for (int c=0;c<4;c++){
        float lg = 40.0f * tanhf(vals[c]);
        unsigned flat = (unsigned)m*1024u + (unsigned)(o0 + tn*4 + c);
        vals[c] = (lg + gumbel_noise(flat)) / 0.1f;
      }
    }
    float4 o = make_float4(vals[0], vals[1], vals[2], vals[3]);
    *(float4*)(out + (size_t)m*ldo + o0 + tn*4) = o;
  }
}

// ---------------- channel attention + combine ----------------
__global__ __launch_bounds__(256) void attn_k(const float* __restrict__ c0,
                                              const float* __restrict__ s0,
                                              const float* __restrict__ s1,
                                              const float* __restrict__ s2,
                                              const float* __restrict__ a2,
                                              float* __restrict__ hp){
  int tid = threadIdx.x, wid = tid >> 6, lane = tid & 63;
  int row = blockIdx.x*4 + wid;
  size_t base = (size_t)row*HD + lane*4;
  float4 av = *(const float4*)(a2 + lane*4);
  float4 v[4];
  v[0] = *(const float4*)(c0 + base);
  v[1] = *(const float4*)(s0 + base);
  v[2] = *(const float4*)(s1 + base);
  v[3] = *(const float4*)(s2 + base);
  float e[4];
  #pragma unroll
  for (int c=0;c<4;c++){
    float p = fmaxf(v[c].x,0.f)*av.x + fmaxf(v[c].y,0.f)*av.y
            + fmaxf(v[c].z,0.f)*av.z + fmaxf(v[c].w,0.f)*av.w;
    e[c] = wave_sum(p);
  }
  float m = fmaxf(fmaxf(e[0],e[1]), fmaxf(e[2],e[3]));
  float w0 = expf(e[0]-m), w1 = expf(e[1]-m), w2 = expf(e[2]-m), w3 = expf(e[3]-m);
  float inv = 0.25f / (w0+w1+w2+w3);
  float4 o;
  o.x = (w0*v[0].x + w1*v[1].x + w2*v[2].x + w3*v[3].x)*inv;
  o.y = (w0*v[0].y + w1*v[1].y + w2*v[2].y + w3*v[3].y)*inv;
  o.z = (w0*v[0].z + w1*v[1].z + w2*v[2].z + w3*v[3].z)*inv;
  o.w = (w0*v[0].w + w1*v[1].w + w2*v[2].w + w3*v[3].w)*inv;
  *(float4*)(hp + base) = o;
}

// ---------------- batched 1024x1024 transpose ----------------
__global__ __launch_bounds__(256) void transpose_k(const float* __restrict__ Z,
                                                   float* __restrict__ Zt){
  __shared__ float tile[64][65];
  int bz = blockIdx.z;
  int i0 = blockIdx.y*64, j0 = blockIdx.x*64;
  const float* Zb = Z  + (size_t)bz*NN*NN;
  float*       Tb = Zt + (size_t)bz*NN*NN;
  int tid = threadIdx.x;
  #pragma unroll
  for (int it=0; it<4; it++){
    int f = tid + it*256;
    int r = f >> 4, c4 = (f & 15)*4;
    float4 v = *(const float4*)(Zb + (size_t)(i0+r)*NN + j0 + c4);
    tile[r][c4+0]=v.x; tile[r][c4+1]=v.y; tile[r][c4+2]=v.z; tile[r][c4+3]=v.w;
  }
  __syncthreads();
  #pragma unroll
  for (int it=0; it<4; it++){
    int f = tid + it*256;
    int r = f >> 4, c4 = (f & 15)*4;
    float4 v = make_float4(tile[c4+0][r], tile[c4+1][r], tile[c4+2][r], tile[c4+3][r]);
    *(float4*)(Tb + (size_t)(j0+r)*NN + i0 + c4) = v;
  }
}

// ---------------- sinkhorn passes ----------------
__global__ __launch_bounds__(256) void lse_rows_k(const float* __restrict__ Z,
                                                  const float* __restrict__ sub,
                                                  float* __restrict__ outv){
  __shared__ float redm[4], reds[4];
  int tid = threadIdx.x, wid = tid >> 6, lane = tid & 63;
  int row = blockIdx.x;
  int b = row >> 10;
  float4 z  = *(const float4*)(Z   + (size_t)row*NN + tid*4);
  float4 s4 = *(const float4*)(sub + (size_t)b*NN   + tid*4);
  float x0 = z.x - s4.x, x1 = z.y - s4.y, x2 = z.z - s4.z, x3 = z.w - s4.w;
  float m = fmaxf(fmaxf(x0,x1), fmaxf(x2,x3));
  m = wave_max(m);
  if (lane==0) redm[wid] = m;
  __syncthreads();
  float M = fmaxf(fmaxf(redm[0],redm[1]), fmaxf(redm[2],redm[3]));
  float s = expf(x0-M) + expf(x1-M) + expf(x2-M) + expf(x3-M);
  s = wave_sum(s);
  if (lane==0) reds[wid] = s;
  __syncthreads();
  if (tid==0) outv[row] = M + logf(reds[0]+reds[1]+reds[2]+reds[3]);
}

__global__ __launch_bounds__(256) void sumexp_rows_k(const float* __restrict__ Zt,
                                                     const float* __restrict__ Lv,
                                                     const float* __restrict__ Cv,
                                                     float* __restrict__ Tv){
  __shared__ float reds[4];
  int tid = threadIdx.x, wid = tid >> 6, lane = tid & 63;
  int row = blockIdx.x;
  int b = row >> 10;
  float sc = Cv[row];
  float4 z  = *(const float4*)(Zt + (size_t)row*NN + tid*4);
  float4 l4 = *(const float4*)(Lv + (size_t)b*NN   + tid*4);
  float s = expf(z.x - l4.x - sc) + expf(z.y - l4.y - sc)
          + expf(z.z - l4.z - sc) + expf(z.w - l4.w - sc);
  s = wave_sum(s);
  if (lane==0) reds[wid] = s;
  __syncthreads();
  if (tid==0) Tv[row] = reds[0]+reds[1]+reds[2]+reds[3];
}

__global__ __launch_bounds__(256) void writep_k(const float* __restrict__ Z,
                                                const float* __restrict__ Cv,
                                                const float* __restrict__ Lv,
                                                const float* __restrict__ Tv,
                                                float* __restrict__ P){
  int gid = blockIdx.x*256 + threadIdx.x;
  int row = gid >> 8;
  int j = (gid & 255)*4;
  int b = row >> 10;
  float4 z = ((const float4*)Z)[gid];
  float4 c = *(const float4*)(Cv + (size_t)b*NN + j);
  float4 t = *(const float4*)(Tv + (size_t)b*NN + j);
  float l = Lv[row];
  float4 o;
  o.x = expf(z.x - c.x - l) / t.x;
  o.y = expf(z.y - c.y - l) / t.y;
  o.z = expf(z.z - c.z - l) / t.z;
  o.w = expf(z.w - c.w - l) / t.w;
  ((float4*)P)[gid] = o;
}

// ---------------- host orchestration ----------------
extern "C" void kernel_launch(void* const* d_in, const int* in_sizes, int n_in,
                              void* d_out, int out_size, void* d_ws, size_t ws_size,
                              hipStream_t stream){
  const float* X    = (const float*)d_in[0];
  const float* adj  = (const float*)d_in[1];
  const float* w_in = (const float*)d_in[2];
  const float* b_in = (const float*)d_in[3];
  const float* cw1  = (const float*)d_in[4];
  const float* cb1  = (const float*)d_in[5];
  const float* cw2  = (const float*)d_in[6];
  const float* cb2  = (const float*)d_in[7];
  const float* ca   = (const float*)d_in[8];
  const float* m1w  = (const float*)d_in[9];
  const float* m1b  = (const float*)d_in[10];
  const float* m2w  = (const float*)d_in[11];
  const float* m2b  = (const float*)d_in[12];

  float* outp = (float*)d_out;
  float* Pout = outp;                              // [0,16M) floats
  float* Z0   = outp + (size_t)16*1024*1024;       // [16M,32M)

  // scratch slots inside d_out (each 4M floats = 16 MB); all dead before Z0/P writes
  const size_t SLOT = (size_t)4*1024*1024;
  float* s1 = outp + 0*SLOT;     // g, t1, t3, S2
  float* s2 = outp + 1*SLOT;     // C0, mlp-mid
  float* s3 = outp + 2*SLOT;     // S0
  float* s4 = outp + 3*SLOT;     // t2, h'
  float* s5 = outp + 4*SLOT;     // S1
  float* s6 = outp + 5*SLOT;     // t4
  unsigned short* adjbf = (unsigned short*)(outp + 6*SLOT);   // 16M bf16 = [96MB,128MB)

  float* ws     = (float*)d_ws;
  float* Zt     = ws;                                   // 16M floats (sinkhorn phase)
  float* hidden = ws;                                   // 12M floats (layers phase)
  float* dis    = ws + (size_t)12*1024*1024;
  float* rinv   = dis + 16384;
  unsigned short* bt = (unsigned short*)(rinv + 16384); // 4M bf16 = 8 MB
  float* Rv = ws + (size_t)16*1024*1024;
  float* Cv = Rv + 16384;
  float* Lv = Cv + 16384;
  float* Tv = Lv + 16384;

  dim3 blk(256);
  dim3 gEw(4096);
  dim3 gMM(2, 8, 16);             // MFMA adj gemm: n-tiles, m-tiles, batch
  dim3 gCT(16, 4, 16);            // bconv_t
  dim3 gRow(MROWS);

  row_stats_k<<<gEw, blk, 0, stream>>>(adj, dis, rinv);
  adj2bf16_k<<<dim3(16384), blk, 0, stream>>>(adj, adjbf);

  // input projection: hidden[:, 0:256] = X @ w_in^T + b_in
  gemm_nt_k<<<dim3(4,256), blk, 0, stream>>>(X, IND, w_in, b_in, hidden, 768, IND, 0);

  for (int l=0; l<2; l++){
    const float* h_in = hidden + l*HD;       // ld 768
    const float* w1 = cw1 + (size_t)l*HD*HD;
    const float* b1 = cb1 + (size_t)l*HD;
    const float* w2 = cw2 + (size_t)l*HD*HD;
    const float* b2 = cb2 + (size_t)l*HD;
    const float* a2 = ca  + (size_t)l*2*HD + HD;

    // g = dis .* h
    scale_rows_k<<<gEw, blk, 0, stream>>>(h_in, 768, dis, s1);
    // C0 = leaky(A_hat h)
    bconv_t_k<<<gCT, blk, 0, stream>>>(s1, HD, bt);
    gemm_nn_mfma_k<<<gMM, dim3(512), 0, stream>>>(adjbf, bt, s1, HD, dis, s2, 0);
    // t1 = P h
    bconv_t_k<<<gCT, blk, 0, stream>>>(h_in, 768, bt);
    gemm_nn_mfma_k<<<gMM, dim3(512), 0, stream>>>(adjbf, bt, h_in, 768, rinv, s1, 1);
    // S0 = |h - t1|
    sub_abs_k<<<gEw, blk, 0, stream>>>(h_in, 768, s1, HD, s3);
    // t2 = P t1
    bconv_t_k<<<gCT, blk, 0, stream>>>(s1, HD, bt);
    gemm_nn_mfma_k<<<gMM, dim3(512), 0, stream>>>(adjbf, bt, s1, HD, rinv, s4, 1);
    // S1 = |t1 - t2|
    sub_abs_k<<<gEw, blk, 0, stream>>>(s1, HD, s4, HD, s5);
    // t3 = P t2
    bconv_t_k<<<gCT, blk, 0, stream>>>(s4, HD, bt);
    gemm_nn_mfma_k<<<gMM, dim3(512), 0, stream>>>(adjbf, bt, s4, HD, rinv, s1, 1);
    // t4 = P t3
    bconv_t_k<<<gCT, blk, 0, stream>>>(s1, HD, bt);
    gemm_nn_mfma_k<<<gMM, dim3(512), 0, stream>>>(adjbf, bt, s1, HD, rinv, s6, 1);
    // S2 = |t2 - t4|
    sub_abs_k<<<gEw, blk, 0, stream>>>(s4, HD, s6, HD, s1);
    // attention combine -> h'
    attn_k<<<gEw, blk, 0, stream>>>(s2, s3, s5, s1, a2, s4);
    // two linears
    gemm_nt_k<<<dim3(4,256), blk, 0, stream>>>(s4, HD, w1, b1, s1, HD, HD, 1);
    gemm_nt_k<<<dim3(4,256), blk, 0, stream>>>(s1, HD, w2, b2, hidden + (l+1)*HD, 768, HD, 1);
  }

  // MLP head
  gemm_nt_k<<<dim3(4,256),  blk, 0, stream>>>(hidden, 768, m1w, m1b, s2, HD, 768, 1);
  gemm_nt_k<<<dim3(16,256), blk, 0, stream>>>(s2, HD, m2w, m2b, Z0, OUTD, HD, 2);

  // Sinkhorn: Z_t = Z0 - R_i - C_j (rank-1 log-space; Z0 read-only)
  transpose_k<<<dim3(16,16,16), blk, 0, stream>>>(Z0, Zt);
  hipMemsetAsync(Cv, 0, MROWS*sizeof(float), stream);
  for (int t=0; t<20; t++){
    lse_rows_k<<<gRow, blk, 0, stream>>>(Z0, Cv, Rv);
    lse_rows_k<<<gRow, blk, 0, stream>>>(Zt, Rv, Cv);
  }
  lse_rows_k<<<gRow, blk, 0, stream>>>(Z0, Cv, Lv);
  sumexp_rows_k<<<gRow, blk, 0, stream>>>(Zt, Lv, Cv, Tv);
  writep_k<<<gRow, blk, 0, stream>>>(Z0, Cv, Lv, Tv, Pout);
}

// Round 4
// 1532.666 us; speedup vs baseline: 1.6414x; 1.1269x over previous
//
#include <hip/hip_runtime.h>
#include <cstdint>
#include <cstddef>

// Problem constants
#define BB 16
#define NN 1024
#define HD 256
#define IND 128
#define OUTD 1024
#define MROWS (BB*NN)          // 16384

#define LEAKY(x) ((x) >= 0.0f ? (x) : 0.01f*(x))

typedef short short8 __attribute__((ext_vector_type(8)));
typedef float f32x4 __attribute__((ext_vector_type(4)));

// ---------------- wave helpers ----------------
__device__ inline float wave_sum(float v){
  #pragma unroll
  for (int off=32; off; off>>=1) v += __shfl_xor(v, off, 64);
  return v;
}
__device__ inline float wave_max(float v){
  #pragma unroll
  for (int off=32; off; off>>=1) v = fmaxf(v, __shfl_xor(v, off, 64));
  return v;
}

// fp32 -> bf16 round-to-nearest-even; bf16 -> fp32
__device__ inline unsigned short f2bf(float x){
  unsigned u = __float_as_uint(x);
  unsigned r = (u + 0x7fffu + ((u >> 16) & 1u)) >> 16;
  return (unsigned short)r;
}
__device__ inline float bf2f(unsigned short h){
  return __uint_as_float((unsigned)h << 16);
}

// ---------------- JAX threefry2x32 gumbel noise (partitionable) ----------------
__device__ inline float gumbel_noise(unsigned m){
  const unsigned k0 = 0u, k1 = 42u;
  const unsigned ks2 = k0 ^ k1 ^ 0x1BD11BDAu;
  unsigned x0 = 0u, x1 = m;
  x0 += k0; x1 += k1;
  #define TF_ROUND(r) { x0 += x1; x1 = (x1 << (r)) | (x1 >> (32-(r))); x1 ^= x0; }
  TF_ROUND(13) TF_ROUND(15) TF_ROUND(26) TF_ROUND(6)
  x0 += k1;  x1 += ks2 + 1u;
  TF_ROUND(17) TF_ROUND(29) TF_ROUND(16) TF_ROUND(24)
  x0 += ks2; x1 += k0 + 2u;
  TF_ROUND(13) TF_ROUND(15) TF_ROUND(26) TF_ROUND(6)
  x0 += k0;  x1 += k1 + 3u;
  TF_ROUND(17) TF_ROUND(29) TF_ROUND(16) TF_ROUND(24)
  x0 += k1;  x1 += ks2 + 4u;
  TF_ROUND(13) TF_ROUND(15) TF_ROUND(26) TF_ROUND(6)
  x0 += ks2; x1 += k0 + 5u;
  #undef TF_ROUND
  unsigned bits = x0 ^ x1;
  float u = __uint_as_float((bits >> 9) | 0x3f800000u) - 1.0f;   // [0,1)
  float t = -logf(u + 1e-20f);
  return -logf(t + 1e-20f) * 0.05f;   // NOISE_SCALE
}

// ---------------- row stats of adj ----------------
__global__ __launch_bounds__(256) void row_stats_k(const float* __restrict__ adj,
                                                   float* __restrict__ dis,
                                                   float* __restrict__ rinv){
  int tid = threadIdx.x, wid = tid >> 6, lane = tid & 63;
  int row = blockIdx.x*4 + wid;
  const float4* rp = (const float4*)(adj + (size_t)row*NN);
  float s = 0.f;
  #pragma unroll
  for (int p=0;p<4;p++){ float4 v = rp[lane + p*64]; s += v.x+v.y+v.z+v.w; }
  s = wave_sum(s);
  if (lane==0){
    dis[row]  = 1.0f/sqrtf(s + 1.0f);
    rinv[row] = 1.0f/s;
  }
}

// ---------------- converts ----------------
__global__ __launch_bounds__(256) void adj2bf16_k(const float* __restrict__ adj,
                                                  unsigned short* __restrict__ abf){
  int gid = blockIdx.x*256 + threadIdx.x;
  float4 v = ((const float4*)adj)[gid];
  ushort4 o;
  o.x = f2bf(v.x); o.y = f2bf(v.y); o.z = f2bf(v.z); o.w = f2bf(v.w);
  ((ushort4*)abf)[gid] = o;
}

// fp32 [16][1024 i][ld] (cols 0..255) -> bf16 transposed [16][256 c][1024 i]
// optional per-row scale (dis): out = bf16(scale_i * in)
__global__ __launch_bounds__(256) void bconv_t_k(const float* __restrict__ in, int ld,
                                                 const float* __restrict__ scale,
                                                 unsigned short* __restrict__ outT){
  __shared__ float tile[64][68];
  int b  = blockIdx.z;
  int i0 = blockIdx.x*64;      // 16 tiles
  int c0 = blockIdx.y*64;      // 4 tiles
  const float* inb = in + (size_t)b*NN*ld;
  unsigned short* ob = outT + (size_t)b*HD*NN;
  int tid = threadIdx.x;
  #pragma unroll
  for (int it=0; it<4; it++){
    int f = tid + it*256;
    int r = f >> 4, c4 = (f & 15)*4;
    float4 v = *(const float4*)(inb + (size_t)(i0+r)*ld + c0 + c4);
    float s = scale ? scale[b*NN + i0 + r] : 1.0f;
    tile[r][c4+0]=v.x*s; tile[r][c4+1]=v.y*s; tile[r][c4+2]=v.z*s; tile[r][c4+3]=v.w*s;
  }
  __syncthreads();
  #pragma unroll
  for (int it=0; it<4; it++){
    int f = tid + it*256;
    int cl = f >> 4, r4 = (f & 15)*4;
    ushort4 o;
    o.x = f2bf(tile[r4+0][cl]);
    o.y = f2bf(tile[r4+1][cl]);
    o.z = f2bf(tile[r4+2][cl]);
    o.w = f2bf(tile[r4+3][cl]);
    *(ushort4*)(ob + (size_t)(c0+cl)*NN + i0 + r4) = o;
  }
}

// ---------------- elementwise ----------------
__global__ __launch_bounds__(256) void sub_abs_k(const float* __restrict__ a, int lda,
                                                 const float* __restrict__ bp, int ldb,
                                                 float* __restrict__ out){
  int gid = blockIdx.x*256 + threadIdx.x;
  int row = gid >> 6, c = (gid & 63)*4;
  float4 va = *(const float4*)(a  + (size_t)row*lda + c);
  float4 vb = *(const float4*)(bp + (size_t)row*ldb + c);
  float4 o = make_float4(fabsf(va.x-vb.x), fabsf(va.y-vb.y), fabsf(va.z-vb.z), fabsf(va.w-vb.w));
  *(float4*)(out + (size_t)row*HD + c) = o;
}

// ---------------- MFMA batched GEMM: acc = adj[b] @ B[b] ----------------
// A bf16 [16][1024][1024]; Bt bf16 [16][256 n][1024 k].
// mode 1: out = 0.5*(Bsrc[i][n] + sc_i*acc)            (lazy walk, Bsrc = h)
// mode 2: out = leaky(sc_i*(acc + sc_i*Bsrc[i][n]))    (GCN, Bsrc = h, g = dis.*h implied)
__global__ __launch_bounds__(512) void gemm_nn_mfma_k(const unsigned short* __restrict__ Abf,
                                                      const unsigned short* __restrict__ Btb,
                                                      const float* __restrict__ Bsrc, int ldb,
                                                      const float* __restrict__ rowscale,
                                                      float* __restrict__ out, int mode){
  __shared__ unsigned short Als[128][40];
  __shared__ unsigned short Bls[128][40];
  int b  = blockIdx.z;
  int n0 = blockIdx.x*128;
  int i0 = blockIdx.y*128;
  const unsigned short* Ab = Abf + (size_t)b*NN*NN + (size_t)i0*NN;
  const unsigned short* Bb = Btb + (size_t)b*HD*NN + (size_t)n0*NN;
  int tid = threadIdx.x;
  int wave = tid >> 6, lane = tid & 63;
  int quad = lane >> 4, l16 = lane & 15;
  int wr = (wave >> 2)*64;
  int wc = (wave & 3)*32;

  f32x4 acc[4][2] = {};

  int sr = tid >> 2, sg = tid & 3;
  for (int kc = 0; kc < NN; kc += 32){
    short8 av = *(const short8*)(Ab + (size_t)sr*NN + kc + sg*8);
    short8 bv = *(const short8*)(Bb + (size_t)sr*NN + kc + sg*8);
    *(short8*)&Als[sr][sg*8] = av;
    *(short8*)&Bls[sr][sg*8] = bv;
    __syncthreads();
    short8 af[4];
    #pragma unroll
    for (int rt=0; rt<4; rt++)
      af[rt] = *(const short8*)&Als[wr + rt*16 + l16][quad*8];
    #pragma unroll
    for (int ct=0; ct<2; ct++){
      short8 bfr = *(const short8*)&Bls[wc + ct*16 + l16][quad*8];
      #pragma unroll
      for (int rt=0; rt<4; rt++)
        acc[rt][ct] = __builtin_amdgcn_mfma_f32_16x16x32_bf16(af[rt], bfr, acc[rt][ct], 0, 0, 0);
    }
    __syncthreads();
  }

  #pragma unroll
  for (int rt=0; rt<4; rt++){
    #pragma unroll
    for (int p=0; p<4; p++){
      int gr = i0 + wr + rt*16 + quad*4 + p;
      int gm = b*NN + gr;
      float sc = rowscale[gm];
      #pragma unroll
      for (int ct=0; ct<2; ct++){
        int gc = n0 + wc + ct*16 + l16;
        float a = acc[rt][ct][p];
        float src = Bsrc[(size_t)gm*ldb + gc];
        float o = (mode == 1) ? 0.5f*(src + sc*a) : LEAKY(sc*(a + sc*src));
        out[(size_t)gm*HD + gc] = o;
      }
    }
  }
}

// ---------------- split-bf16 MFMA linear: out = act(Ain @ W^T + bias) ----------------
// A [M,K] fp32 (lda), W [O,K] fp32 row-major. hi/lo bf16 decomposition in LDS,
// 3 MFMA passes: ah*bh + al*bh + ah*bl  (fp32-class accuracy at ~790 TF).
// act 0: none, 1: leaky, 2: sinkhorn init (Z0 = (40*tanh(x)+gumbel)/0.1)
__global__ __launch_bounds__(512) void gemm_nt_mfma_k(const float* __restrict__ Ain, int lda,
                                                      const float* __restrict__ W,
                                                      const float* __restrict__ bias,
                                                      float* __restrict__ out, int ldo,
                                                      int K, int act){
  __shared__ unsigned short Ah[128][40], Al[128][40], Bh[128][40], Bl[128][40];
  int o0 = blockIdx.x*128, m0 = blockIdx.y*128;
  int tid = threadIdx.x;
  int wave = tid >> 6, lane = tid & 63;
  int quad = lane >> 4, l16 = lane & 15;
  int wr = (wave >> 2)*64;
  int wc = (wave & 3)*32;

  f32x4 acc[4][2] = {};

  for (int kc = 0; kc < K; kc += 32){
    #pragma unroll
    for (int it=0; it<2; it++){
      int f = tid + it*512;
      int r = f >> 3, c4 = (f & 7)*4;
      float4 va = *(const float4*)(Ain + (size_t)(m0+r)*lda + kc + c4);
      ushort4 h, lo;
      h.x = f2bf(va.x); lo.x = f2bf(va.x - bf2f(h.x));
      h.y = f2bf(va.y); lo.y = f2bf(va.y - bf2f(h.y));
      h.z = f2bf(va.z); lo.z = f2bf(va.z - bf2f(h.z));
      h.w = f2bf(va.w); lo.w = f2bf(va.w - bf2f(h.w));
      *(ushort4*)&Ah[r][c4] = h;
      *(ushort4*)&Al[r][c4] = lo;
      float4 vb = *(const float4*)(W + (size_t)(o0+r)*K + kc + c4);
      h.x = f2bf(vb.x); lo.x = f2bf(vb.x - bf2f(h.x));
      h.y = f2bf(vb.y); lo.y = f2bf(vb.y - bf2f(h.y));
      h.z = f2bf(vb.z); lo.z = f2bf(vb.z - bf2f(h.z));
      h.w = f2bf(vb.w); lo.w = f2bf(vb.w - bf2f(h.w));
      *(ushort4*)&Bh[r][c4] = h;
      *(ushort4*)&Bl[r][c4] = lo;
    }
    __syncthreads();
    short8 ah[4], al[4];
    #pragma unroll
    for (int rt=0; rt<4; rt++){
      ah[rt] = *(const short8*)&Ah[wr + rt*16 + l16][quad*8];
      al[rt] = *(const short8*)&Al[wr + rt*16 + l16][quad*8];
    }
    #pragma unroll
    for (int ct=0; ct<2; ct++){
      short8 bh = *(const short8*)&Bh[wc + ct*16 + l16][quad*8];
      short8 bl = *(const short8*)&Bl[wc + ct*16 + l16][quad*8];
      #pragma unroll
      for (int rt=0; rt<4; rt++){
        acc[rt][ct] = __builtin_amdgcn_mfma_f32_16x16x32_bf16(ah[rt], bh, acc[rt][ct], 0, 0, 0);
        acc[rt][ct] = __builtin_amdgcn_mfma_f32_16x16x32_bf16(al[rt], bh, acc[rt][ct], 0, 0, 0);
        acc[rt][ct] = __builtin_amdgcn_mfma_f32_16x16x32_bf16(ah[rt], bl, acc[rt][ct], 0, 0, 0);
      }
    }
    __syncthreads();
  }

  #pragma unroll
  for (int rt=0; rt<4; rt++){
    #pragma unroll
    for (int p=0; p<4; p++){
      int gm = m0 + wr + rt*16 + quad*4 + p;
      #pragma unroll
      for (int ct=0; ct<2; ct++){
        int gc = o0 + wc + ct*16 + l16;
        float v = acc[rt][ct][p] + bias[gc];
        if (act == 1){
          v = LEAKY(v);
        } else if (act == 2){
          float lg = 40.0f * tanhf(v);
          unsigned flat = (unsigned)gm*1024u + (unsigned)gc;
          v = (lg + gumbel_noise(flat)) / 0.1f;
        }
        out[(size_t)gm*ldo + gc] = v;
      }
    }
  }
}

// ---------------- channel attention + combine ----------------
__global__ __launch_bounds__(256) void attn_k(const float* __restrict__ c0,
                                              const float* __restrict__ s0,
                                              const float* __restrict__ s1,
                                              const float* __restrict__ s2,
                                              const float* __restrict__ a2,
                                              float* __restrict__ hp){
  int tid = threadIdx.x, wid = tid >> 6, lane = tid & 63;
  int row = blockIdx.x*4 + wid;
  size_t base = (size_t)row*HD + lane*4;
  float4 av = *(const float4*)(a2 + lane*4);
  float4 v[4];
  v[0] = *(const float4*)(c0 + base);
  v[1] = *(const float4*)(s0 + base);
  v[2] = *(const float4*)(s1 + base);
  v[3] = *(const float4*)(s2 + base);
  float e[4];
  #pragma unroll
  for (int c=0;c<4;c++){
    float p = fmaxf(v[c].x,0.f)*av.x + fmaxf(v[c].y,0.f)*av.y
            + fmaxf(v[c].z,0.f)*av.z + fmaxf(v[c].w,0.f)*av.w;
    e[c] = wave_sum(p);
  }
  float m = fmaxf(fmaxf(e[0],e[1]), fmaxf(e[2],e[3]));
  float w0 = expf(e[0]-m), w1 = expf(e[1]-m), w2 = expf(e[2]-m), w3 = expf(e[3]-m);
  float inv = 0.25f / (w0+w1+w2+w3);
  float4 o;
  o.x = (w0*v[0].x + w1*v[1].x + w2*v[2].x + w3*v[3].x)*inv;
  o.y = (w0*v[0].y + w1*v[1].y + w2*v[2].y + w3*v[3].y)*inv;
  o.z = (w0*v[0].z + w1*v[1].z + w2*v[2].z + w3*v[3].z)*inv;
  o.w = (w0*v[0].w + w1*v[1].w + w2*v[2].w + w3*v[3].w)*inv;
  *(float4*)(hp + base) = o;
}

// ---------------- batched 1024x1024 transpose ----------------
__global__ __launch_bounds__(256) void transpose_k(const float* __restrict__ Z,
                                                   float* __restrict__ Zt){
  __shared__ float tile[64][65];
  int bz = blockIdx.z;
  int i0 = blockIdx.y*64, j0 = blockIdx.x*64;
  const float* Zb = Z  + (size_t)bz*NN*NN;
  float*       Tb = Zt + (size_t)bz*NN*NN;
  int tid = threadIdx.x;
  #pragma unroll
  for (int it=0; it<4; it++){
    int f = tid + it*256;
    int r = f >> 4, c4 = (f & 15)*4;
    float4 v = *(const float4*)(Zb + (size_t)(i0+r)*NN + j0 + c4);
    tile[r][c4+0]=v.x; tile[r][c4+1]=v.y; tile[r][c4+2]=v.z; tile[r][c4+3]=v.w;
  }
  __syncthreads();
  #pragma unroll
  for (int it=0; it<4; it++){
    int f = tid + it*256;
    int r = f >> 4, c4 = (f & 15)*4;
    float4 v = make_float4(tile[c4+0][r], tile[c4+1][r], tile[c4+2][r], tile[c4+3][r]);
    *(float4*)(Tb + (size_t)(j0+r)*NN + i0 + c4) = v;
  }
}

// ---------------- sinkhorn passes ----------------
__global__ __launch_bounds__(256) void lse_rows_k(const float* __restrict__ Z,
                                                  const float* __restrict__ sub,
                                                  float* __restrict__ outv){
  __shared__ float redm[4], reds[4];
  int tid = threadIdx.x, wid = tid >> 6, lane = tid & 63;
  int row = blockIdx.x;
  int b = row >> 10;
  float4 z  = *(const float4*)(Z   + (size_t)row*NN + tid*4);
  float4 s4 = *(const float4*)(sub + (size_t)b*NN   + tid*4);
  float x0 = z.x - s4.x, x1 = z.y - s4.y, x2 = z.z - s4.z, x3 = z.w - s4.w;
  float m = fmaxf(fmaxf(x0,x1), fmaxf(x2,x3));
  m = wave_max(m);
  if (lane==0) redm[wid] = m;
  __syncthreads();
  float M = fmaxf(fmaxf(redm[0],redm[1]), fmaxf(redm[2],redm[3]));
  float s = expf(x0-M) + expf(x1-M) + expf(x2-M) + expf(x3-M);
  s = wave_sum(s);
  if (lane==0) reds[wid] = s;
  __syncthreads();
  if (tid==0) outv[row] = M + logf(reds[0]+reds[1]+reds[2]+reds[3]);
}

__global__ __launch_bounds__(256) void sumexp_rows_k(const float* __restrict__ Zt,
                                                     const float* __restrict__ Lv,
                                                     const float* __restrict__ Cv,
                                                     float* __restrict__ Tv){
  __shared__ float reds[4];
  int tid = threadIdx.x, wid = tid >> 6, lane = tid & 63;
  int row = blockIdx.x;
  int b = row >> 10;
  float sc = Cv[row];
  float4 z  = *(const float4*)(Zt + (size_t)row*NN + tid*4);
  float4 l4 = *(const float4*)(Lv + (size_t)b*NN   + tid*4);
  float s = expf(z.x - l4.x - sc) + expf(z.y - l4.y - sc)
          + expf(z.z - l4.z - sc) + expf(z.w - l4.w - sc);
  s = wave_sum(s);
  if (lane==0) reds[wid] = s;
  __syncthreads();
  if (tid==0) Tv[row] = reds[0]+reds[1]+reds[2]+reds[3];
}

__global__ __launch_bounds__(256) void writep_k(const float* __restrict__ Z,
                                                const float* __restrict__ Cv,
                                                const float* __restrict__ Lv,
                                                const float* __restrict__ Tv,
                                                float* __restrict__ P){
  int gid = blockIdx.x*256 + threadIdx.x;
  int row = gid >> 8;
  int j = (gid & 255)*4;
  int b = row >> 10;
  float4 z = ((const float4*)Z)[gid];
  float4 c = *(const float4*)(Cv + (size_t)b*NN + j);
  float4 t = *(const float4*)(Tv + (size_t)b*NN + j);
  float l = Lv[row];
  float4 o;
  o.x = expf(z.x - c.x - l) / t.x;
  o.y = expf(z.y - c.y - l) / t.y;
  o.z = expf(z.z - c.z - l) / t.z;
  o.w = expf(z.w - c.w - l) / t.w;
  ((float4*)P)[gid] = o;
}

// ---------------- host orchestration ----------------
extern "C" void kernel_launch(void* const* d_in, const int* in_sizes, int n_in,
                              void* d_out, int out_size, void* d_ws, size_t ws_size,
                              hipStream_t stream){
  const float* X    = (const float*)d_in[0];
  const float* adj  = (const float*)d_in[1];
  const float* w_in = (const float*)d_in[2];
  const float* b_in = (const float*)d_in[3];
  const float* cw1  = (const float*)d_in[4];
  const float* cb1  = (const float*)d_in[5];
  const float* cw2  = (const float*)d_in[6];
  const float* cb2  = (const float*)d_in[7];
  const float* ca   = (const float*)d_in[8];
  const float* m1w  = (const float*)d_in[9];
  const float* m1b  = (const float*)d_in[10];
  const float* m2w  = (const float*)d_in[11];
  const float* m2b  = (const float*)d_in[12];

  float* outp = (float*)d_out;
  float* Pout = outp;                              // [0,16M) floats
  float* Z0   = outp + (size_t)16*1024*1024;       // [16M,32M)

  // scratch slots inside d_out (each 4M floats = 16 MB); dead before Z0/P writes
  const size_t SLOT = (size_t)4*1024*1024;
  float* s1 = outp + 0*SLOT;
  float* s2 = outp + 1*SLOT;
  float* s3 = outp + 2*SLOT;
  float* s4 = outp + 3*SLOT;
  float* s5 = outp + 4*SLOT;
  float* s6 = outp + 5*SLOT;
  unsigned short* adjbf = (unsigned short*)(outp + 6*SLOT);   // 16M bf16 = 32 MB

  float* ws     = (float*)d_ws;
  float* Zt     = ws;                                   // 16M floats (sinkhorn phase)
  float* hidden = ws;                                   // 12M floats (layers phase)
  float* dis    = ws + (size_t)12*1024*1024;
  float* rinv   = dis + 16384;
  unsigned short* bt = (unsigned short*)(rinv + 16384); // 4M bf16 = 8 MB
  float* Rv = ws + (size_t)16*1024*1024;
  float* Cv = Rv + 16384;
  float* Lv = Cv + 16384;
  float* Tv = Lv + 16384;

  dim3 blk(256);
  dim3 gEw(4096);
  dim3 gMM(2, 8, 16);             // MFMA adj gemm
  dim3 gCT(16, 4, 16);            // bconv_t
  dim3 gRow(MROWS);

  row_stats_k<<<gEw, blk, 0, stream>>>(adj, dis, rinv);
  adj2bf16_k<<<dim3(16384), blk, 0, stream>>>(adj, adjbf);

  // input projection: hidden[:, 0:256] = X @ w_in^T + b_in
  gemm_nt_mfma_k<<<dim3(2,128), dim3(512), 0, stream>>>(X, IND, w_in, b_in, hidden, 768, IND, 0);

  for (int l=0; l<2; l++){
    const float* h_in = hidden + l*HD;       // ld 768
    const float* w1 = cw1 + (size_t)l*HD*HD;
    const float* b1 = cb1 + (size_t)l*HD;
    const float* w2 = cw2 + (size_t)l*HD*HD;
    const float* b2 = cb2 + (size_t)l*HD;
    const float* a2 = ca  + (size_t)l*2*HD + HD;   // x-part cancels in channel softmax

    // C0 = leaky(A_hat h): bt = bf16(dis.*h), epilogue re-applies dis to src
    bconv_t_k<<<gCT, blk, 0, stream>>>(h_in, 768, dis, bt);
    gemm_nn_mfma_k<<<gMM, dim3(512), 0, stream>>>(adjbf, bt, h_in, 768, dis, s2, 2);
    // t1 = P h
    bconv_t_k<<<gCT, blk, 0, stream>>>(h_in, 768, nullptr, bt);
    gemm_nn_mfma_k<<<gMM, dim3(512), 0, stream>>>(adjbf, bt, h_in, 768, rinv, s1, 1);
    // S0 = |h - t1|
    sub_abs_k<<<gEw, blk, 0, stream>>>(h_in, 768, s1, HD, s3);
    // t2 = P t1
    bconv_t_k<<<gCT, blk, 0, stream>>>(s1, HD, nullptr, bt);
    gemm_nn_mfma_k<<<gMM, dim3(512), 0, stream>>>(adjbf, bt, s1, HD, rinv, s4, 1);
    // S1 = |t1 - t2|
    sub_abs_k<<<gEw, blk, 0, stream>>>(s1, HD, s4, HD, s5);
    // t3 = P t2
    bconv_t_k<<<gCT, blk, 0, stream>>>(s4, HD, nullptr, bt);
    gemm_nn_mfma_k<<<gMM, dim3(512), 0, stream>>>(adjbf, bt, s4, HD, rinv, s1, 1);
    // t4 = P t3
    bconv_t_k<<<gCT, blk, 0, stream>>>(s1, HD, nullptr, bt);
    gemm_nn_mfma_k<<<gMM, dim3(512), 0, stream>>>(adjbf, bt, s1, HD, rinv, s6, 1);
    // S2 = |t2 - t4|
    sub_abs_k<<<gEw, blk, 0, stream>>>(s4, HD, s6, HD, s1);
    // attention combine -> h'
    attn_k<<<gEw, blk, 0, stream>>>(s2, s3, s5, s1, a2, s4);
    // two linears (split-bf16 MFMA)
    gemm_nt_mfma_k<<<dim3(2,128), dim3(512), 0, stream>>>(s4, HD, w1, b1, s1, HD, HD, 1);
    gemm_nt_mfma_k<<<dim3(2,128), dim3(512), 0, stream>>>(s1, HD, w2, b2, hidden + (l+1)*HD, 768, HD, 1);
  }

  // MLP head
  gemm_nt_mfma_k<<<dim3(2,128), dim3(512), 0, stream>>>(hidden, 768, m1w, m1b, s2, HD, 768, 1);
  gemm_nt_mfma_k<<<dim3(8,128), dim3(512), 0, stream>>>(s2, HD, m2w, m2b, Z0, OUTD, HD, 2);

  // Sinkhorn: Z_t = Z0 - R_i - C_j (rank-1 log-space; Z0 read-only)
  transpose_k<<<dim3(16,16,16), blk, 0, stream>>>(Z0, Zt);
  hipMemsetAsync(Cv, 0, MROWS*sizeof(float), stream);
  for (int t=0; t<20; t++){
    lse_rows_k<<<gRow, blk, 0, stream>>>(Z0, Cv, Rv);
    lse_rows_k<<<gRow, blk, 0, stream>>>(Zt, Rv, Cv);
  }
  lse_rows_k<<<gRow, blk, 0, stream>>>(Z0, Cv, Lv);
  sumexp_rows_k<<<gRow, blk, 0, stream>>>(Zt, Lv, Cv, Tv);
  writep_k<<<gRow, blk, 0, stream>>>(Z0, Cv, Lv, Tv, Pout);
}

// Round 5
// 1507.603 us; speedup vs baseline: 1.6687x; 1.0166x over previous
//
#include <hip/hip_runtime.h>
#include <cstdint>
#include <cstddef>

// Problem constants
#define BB 16
#define NN 1024
#define HD 256
#define IND 128
#define OUTD 1024
#define MROWS (BB*NN)          // 16384

#define LEAKY(x) ((x) >= 0.0f ? (x) : 0.01f*(x))

typedef short short8 __attribute__((ext_vector_type(8)));
typedef float f32x4 __attribute__((ext_vector_type(4)));

// ---------------- wave helpers ----------------
__device__ inline float wave_sum(float v){
  #pragma unroll
  for (int off=32; off; off>>=1) v += __shfl_xor(v, off, 64);
  return v;
}
__device__ inline float wave_max(float v){
  #pragma unroll
  for (int off=32; off; off>>=1) v = fmaxf(v, __shfl_xor(v, off, 64));
  return v;
}

// fp32 -> bf16 round-to-nearest-even; bf16 -> fp32
__device__ inline unsigned short f2bf(float x){
  unsigned u = __float_as_uint(x);
  unsigned r = (u + 0x7fffu + ((u >> 16) & 1u)) >> 16;
  return (unsigned short)r;
}
__device__ inline float bf2f(unsigned short h){
  return __uint_as_float((unsigned)h << 16);
}

// ---------------- JAX threefry2x32 gumbel noise (partitionable) ----------------
__device__ inline float gumbel_noise(unsigned m){
  const unsigned k0 = 0u, k1 = 42u;
  const unsigned ks2 = k0 ^ k1 ^ 0x1BD11BDAu;
  unsigned x0 = 0u, x1 = m;
  x0 += k0; x1 += k1;
  #define TF_ROUND(r) { x0 += x1; x1 = (x1 << (r)) | (x1 >> (32-(r))); x1 ^= x0; }
  TF_ROUND(13) TF_ROUND(15) TF_ROUND(26) TF_ROUND(6)
  x0 += k1;  x1 += ks2 + 1u;
  TF_ROUND(17) TF_ROUND(29) TF_ROUND(16) TF_ROUND(24)
  x0 += ks2; x1 += k0 + 2u;
  TF_ROUND(13) TF_ROUND(15) TF_ROUND(26) TF_ROUND(6)
  x0 += k0;  x1 += k1 + 3u;
  TF_ROUND(17) TF_ROUND(29) TF_ROUND(16) TF_ROUND(24)
  x0 += k1;  x1 += ks2 + 4u;
  TF_ROUND(13) TF_ROUND(15) TF_ROUND(26) TF_ROUND(6)
  x0 += ks2; x1 += k0 + 5u;
  #undef TF_ROUND
  unsigned bits = x0 ^ x1;
  float u = __uint_as_float((bits >> 9) | 0x3f800000u) - 1.0f;   // [0,1)
  float t = -logf(u + 1e-20f);
  return -logf(t + 1e-20f) * 0.05f;   // NOISE_SCALE
}

// ---------------- fused adj row stats + bf16 convert ----------------
// one wave per adj row: dis/rinv + adjbf (adj read once)
__global__ __launch_bounds__(256) void adj_prep_k(const float* __restrict__ adj,
                                                  float* __restrict__ dis,
                                                  float* __restrict__ rinv,
                                                  unsigned short* __restrict__ abf){
  int tid = threadIdx.x, wid = tid >> 6, lane = tid & 63;
  int row = blockIdx.x*4 + wid;
  const float4* rp = (const float4*)(adj + (size_t)row*NN);
  ushort4* op = (ushort4*)(abf + (size_t)row*NN);
  float s = 0.f;
  #pragma unroll
  for (int p=0;p<4;p++){
    float4 v = rp[lane + p*64];
    s += v.x+v.y+v.z+v.w;
    ushort4 o;
    o.x = f2bf(v.x); o.y = f2bf(v.y); o.z = f2bf(v.z); o.w = f2bf(v.w);
    op[lane + p*64] = o;
  }
  s = wave_sum(s);
  if (lane==0){
    dis[row]  = 1.0f/sqrtf(s + 1.0f);
    rinv[row] = 1.0f/s;
  }
}

// ---------------- flat hi/lo split (weights, mlp2 input) ----------------
__global__ __launch_bounds__(256) void split_flat_k(const float* __restrict__ src,
                                                    unsigned short* __restrict__ h,
                                                    unsigned short* __restrict__ l,
                                                    int n4){
  int gid = blockIdx.x*256 + threadIdx.x;
  if (gid >= n4) return;
  float4 v = ((const float4*)src)[gid];
  ushort4 hh, ll;
  hh.x = f2bf(v.x); ll.x = f2bf(v.x - bf2f(hh.x));
  hh.y = f2bf(v.y); ll.y = f2bf(v.y - bf2f(hh.y));
  hh.z = f2bf(v.z); ll.z = f2bf(v.z - bf2f(hh.z));
  hh.w = f2bf(v.w); ll.w = f2bf(v.w - bf2f(hh.w));
  ((ushort4*)h)[gid] = hh;
  ((ushort4*)l)[gid] = ll;
}

// fp32 [16][1024 i][ld] (cols 0..255) -> bf16 transposed [16][256 c][1024 i]
// optional per-row scale (dis): out = bf16(scale_i * in)
__global__ __launch_bounds__(256) void bconv_t_k(const float* __restrict__ in, int ld,
                                                 const float* __restrict__ scale,
                                                 unsigned short* __restrict__ outT){
  __shared__ float tile[64][68];
  int b  = blockIdx.z;
  int i0 = blockIdx.x*64;      // 16 tiles
  int c0 = blockIdx.y*64;      // 4 tiles
  const float* inb = in + (size_t)b*NN*ld;
  unsigned short* ob = outT + (size_t)b*HD*NN;
  int tid = threadIdx.x;
  #pragma unroll
  for (int it=0; it<4; it++){
    int f = tid + it*256;
    int r = f >> 4, c4 = (f & 15)*4;
    float4 v = *(const float4*)(inb + (size_t)(i0+r)*ld + c0 + c4);
    float s = scale ? scale[b*NN + i0 + r] : 1.0f;
    tile[r][c4+0]=v.x*s; tile[r][c4+1]=v.y*s; tile[r][c4+2]=v.z*s; tile[r][c4+3]=v.w*s;
  }
  __syncthreads();
  #pragma unroll
  for (int it=0; it<4; it++){
    int f = tid + it*256;
    int cl = f >> 4, r4 = (f & 15)*4;
    ushort4 o;
    o.x = f2bf(tile[r4+0][cl]);
    o.y = f2bf(tile[r4+1][cl]);
    o.z = f2bf(tile[r4+2][cl]);
    o.w = f2bf(tile[r4+3][cl]);
    *(ushort4*)(ob + (size_t)(c0+cl)*NN + i0 + r4) = o;
  }
}

// ---------------- elementwise ----------------
__global__ __launch_bounds__(256) void sub_abs_k(const float* __restrict__ a, int lda,
                                                 const float* __restrict__ bp, int ldb,
                                                 float* __restrict__ out){
  int gid = blockIdx.x*256 + threadIdx.x;
  int row = gid >> 6, c = (gid & 63)*4;
  float4 va = *(const float4*)(a  + (size_t)row*lda + c);
  float4 vb = *(const float4*)(bp + (size_t)row*ldb + c);
  float4 o = make_float4(fabsf(va.x-vb.x), fabsf(va.y-vb.y), fabsf(va.z-vb.z), fabsf(va.w-vb.w));
  *(float4*)(out + (size_t)row*HD + c) = o;
}

// ---------------- MFMA batched GEMM: acc = adj[b] @ B[b] ----------------
// mode 1: out = 0.5*(Bsrc[i][n] + sc_i*acc)            (lazy walk, Bsrc = h)
// mode 2: out = leaky(sc_i*(acc + sc_i*Bsrc[i][n]))    (GCN, g = dis.*h implied)
__global__ __launch_bounds__(512) void gemm_nn_mfma_k(const unsigned short* __restrict__ Abf,
                                                      const unsigned short* __restrict__ Btb,
                                                      const float* __restrict__ Bsrc, int ldb,
                                                      const float* __restrict__ rowscale,
                                                      float* __restrict__ out, int mode){
  __shared__ unsigned short Als[128][40];
  __shared__ unsigned short Bls[128][40];
  int b  = blockIdx.z;
  int n0 = blockIdx.x*128;
  int i0 = blockIdx.y*128;
  const unsigned short* Ab = Abf + (size_t)b*NN*NN + (size_t)i0*NN;
  const unsigned short* Bb = Btb + (size_t)b*HD*NN + (size_t)n0*NN;
  int tid = threadIdx.x;
  int wave = tid >> 6, lane = tid & 63;
  int quad = lane >> 4, l16 = lane & 15;
  int wr = (wave >> 2)*64;
  int wc = (wave & 3)*32;

  f32x4 acc[4][2] = {};

  int sr = tid >> 2, sg = tid & 3;
  for (int kc = 0; kc < NN; kc += 32){
    short8 av = *(const short8*)(Ab + (size_t)sr*NN + kc + sg*8);
    short8 bv = *(const short8*)(Bb + (size_t)sr*NN + kc + sg*8);
    *(short8*)&Als[sr][sg*8] = av;
    *(short8*)&Bls[sr][sg*8] = bv;
    __syncthreads();
    short8 af[4];
    #pragma unroll
    for (int rt=0; rt<4; rt++)
      af[rt] = *(const short8*)&Als[wr + rt*16 + l16][quad*8];
    #pragma unroll
    for (int ct=0; ct<2; ct++){
      short8 bfr = *(const short8*)&Bls[wc + ct*16 + l16][quad*8];
      #pragma unroll
      for (int rt=0; rt<4; rt++)
        acc[rt][ct] = __builtin_amdgcn_mfma_f32_16x16x32_bf16(af[rt], bfr, acc[rt][ct], 0, 0, 0);
    }
    __syncthreads();
  }

  #pragma unroll
  for (int rt=0; rt<4; rt++){
    #pragma unroll
    for (int p=0; p<4; p++){
      int gr = i0 + wr + rt*16 + quad*4 + p;
      int gm = b*NN + gr;
      float sc = rowscale[gm];
      #pragma unroll
      for (int ct=0; ct<2; ct++){
        int gc = n0 + wc + ct*16 + l16;
        float a = acc[rt][ct][p];
        float src = Bsrc[(size_t)gm*ldb + gc];
        float o = (mode == 1) ? 0.5f*(src + sc*a) : LEAKY(sc*(a + sc*src));
        out[(size_t)gm*HD + gc] = o;
      }
    }
  }
}

// ---------------- split-bf16 MFMA linear: out = act(Ain @ W^T + bias) ----------------
// W pre-split (Wh/Wl [O][K] bf16). A either pre-split (Ah_/Al_) or fp32 (Ain,
// split in-kernel). 3 MFMA passes: ah*bh + al*bh + ah*bl.
// act 0: none, 1: leaky, 2: sinkhorn init (Z0 = (40*tanh(x)+gumbel)/0.1)
__global__ __launch_bounds__(512) void gemm_nt_mfma_k(const float* __restrict__ Ain,
                                                      const unsigned short* __restrict__ Ah_,
                                                      const unsigned short* __restrict__ Al_,
                                                      int lda,
                                                      const unsigned short* __restrict__ Wh_,
                                                      const unsigned short* __restrict__ Wl_,
                                                      const float* __restrict__ bias,
                                                      float* __restrict__ out, int ldo,
                                                      int K, int act){
  __shared__ unsigned short Ah[128][40], Al[128][40], Bh[128][40], Bl[128][40];
  int o0 = blockIdx.x*128, m0 = blockIdx.y*128;
  int tid = threadIdx.x;
  int wave = tid >> 6, lane = tid & 63;
  int quad = lane >> 4, l16 = lane & 15;
  int wr = (wave >> 2)*64;
  int wc = (wave & 3)*32;
  int sr = tid >> 2, sg = tid & 3;

  f32x4 acc[4][2] = {};

  for (int kc = 0; kc < K; kc += 32){
    // W tiles: pure bf16 loads
    *(short8*)&Bh[sr][sg*8] = *(const short8*)(Wh_ + (size_t)(o0+sr)*K + kc + sg*8);
    *(short8*)&Bl[sr][sg*8] = *(const short8*)(Wl_ + (size_t)(o0+sr)*K + kc + sg*8);
    // A tile: pre-split loads or in-kernel decomposition
    if (Ah_){
      *(short8*)&Ah[sr][sg*8] = *(const short8*)(Ah_ + (size_t)(m0+sr)*lda + kc + sg*8);
      *(short8*)&Al[sr][sg*8] = *(const short8*)(Al_ + (size_t)(m0+sr)*lda + kc + sg*8);
    } else {
      #pragma unroll
      for (int it=0; it<2; it++){
        int f = tid + it*512;
        int r = f >> 3, c4 = (f & 7)*4;
        float4 va = *(const float4*)(Ain + (size_t)(m0+r)*lda + kc + c4);
        ushort4 h, lo;
        h.x = f2bf(va.x); lo.x = f2bf(va.x - bf2f(h.x));
        h.y = f2bf(va.y); lo.y = f2bf(va.y - bf2f(h.y));
        h.z = f2bf(va.z); lo.z = f2bf(va.z - bf2f(h.z));
        h.w = f2bf(va.w); lo.w = f2bf(va.w - bf2f(h.w));
        *(ushort4*)&Ah[r][c4] = h;
        *(ushort4*)&Al[r][c4] = lo;
      }
    }
    __syncthreads();
    short8 ah[4], al[4];
    #pragma unroll
    for (int rt=0; rt<4; rt++){
      ah[rt] = *(const short8*)&Ah[wr + rt*16 + l16][quad*8];
      al[rt] = *(const short8*)&Al[wr + rt*16 + l16][quad*8];
    }
    #pragma unroll
    for (int ct=0; ct<2; ct++){
      short8 bh = *(const short8*)&Bh[wc + ct*16 + l16][quad*8];
      short8 bl = *(const short8*)&Bl[wc + ct*16 + l16][quad*8];
      #pragma unroll
      for (int rt=0; rt<4; rt++){
        acc[rt][ct] = __builtin_amdgcn_mfma_f32_16x16x32_bf16(ah[rt], bh, acc[rt][ct], 0, 0, 0);
        acc[rt][ct] = __builtin_amdgcn_mfma_f32_16x16x32_bf16(al[rt], bh, acc[rt][ct], 0, 0, 0);
        acc[rt][ct] = __builtin_amdgcn_mfma_f32_16x16x32_bf16(ah[rt], bl, acc[rt][ct], 0, 0, 0);
      }
    }
    __syncthreads();
  }

  #pragma unroll
  for (int rt=0; rt<4; rt++){
    #pragma unroll
    for (int p=0; p<4; p++){
      int gm = m0 + wr + rt*16 + quad*4 + p;
      #pragma unroll
      for (int ct=0; ct<2; ct++){
        int gc = o0 + wc + ct*16 + l16;
        float v = acc[rt][ct][p] + bias[gc];
        if (act == 1){
          v = LEAKY(v);
        } else if (act == 2){
          float lg = 40.0f * tanhf(v);
          unsigned flat = (unsigned)gm*1024u + (unsigned)gc;
          v = (lg + gumbel_noise(flat)) / 0.1f;
        }
        out[(size_t)gm*ldo + gc] = v;
      }
    }
  }
}

// ---------------- channel attention + combine ----------------
__global__ __launch_bounds__(256) void attn_k(const float* __restrict__ c0,
                                              const float* __restrict__ s0,
                                              const float* __restrict__ s1,
                                              const float* __restrict__ s2,
                                              const float* __restrict__ a2,
                                              float* __restrict__ hp){
  int tid = threadIdx.x, wid = tid >> 6, lane = tid & 63;
  int row = blockIdx.x*4 + wid;
  size_t base = (size_t)row*HD + lane*4;
  float4 av = *(const float4*)(a2 + lane*4);
  float4 v[4];
  v[0] = *(const float4*)(c0 + base);
  v[1] = *(const float4*)(s0 + base);
  v[2] = *(const float4*)(s1 + base);
  v[3] = *(const float4*)(s2 + base);
  float e[4];
  #pragma unroll
  for (int c=0;c<4;c++){
    float p = fmaxf(v[c].x,0.f)*av.x + fmaxf(v[c].y,0.f)*av.y
            + fmaxf(v[c].z,0.f)*av.z + fmaxf(v[c].w,0.f)*av.w;
    e[c] = wave_sum(p);
  }
  float m = fmaxf(fmaxf(e[0],e[1]), fmaxf(e[2],e[3]));
  float w0 = expf(e[0]-m), w1 = expf(e[1]-m), w2 = expf(e[2]-m), w3 = expf(e[3]-m);
  float inv = 0.25f / (w0+w1+w2+w3);
  float4 o;
  o.x = (w0*v[0].x + w1*v[1].x + w2*v[2].x + w3*v[3].x)*inv;
  o.y = (w0*v[0].y + w1*v[1].y + w2*v[2].y + w3*v[3].y)*inv;
  o.z = (w0*v[0].z + w1*v[1].z + w2*v[2].z + w3*v[3].z)*inv;
  o.w = (w0*v[0].w + w1*v[1].w + w2*v[2].w + w3*v[3].w)*inv;
  *(float4*)(hp + base) = o;
}

// ---------------- batched 1024x1024 transpose ----------------
__global__ __launch_bounds__(256) void transpose_k(const float* __restrict__ Z,
                                                   float* __restrict__ Zt){
  __shared__ float tile[64][65];
  int bz = blockIdx.z;
  int i0 = blockIdx.y*64, j0 = blockIdx.x*64;
  const float* Zb = Z  + (size_t)bz*NN*NN;
  float*       Tb = Zt + (size_t)bz*NN*NN;
  int tid = threadIdx.x;
  #pragma unroll
  for (int it=0; it<4; it++){
    int f = tid + it*256;
    int r = f >> 4, c4 = (f & 15)*4;
    float4 v = *(const float4*)(Zb + (size_t)(i0+r)*NN + j0 + c4);
    tile[r][c4+0]=v.x; tile[r][c4+1]=v.y; tile[r][c4+2]=v.z; tile[r][c4+3]=v.w;
  }
  __syncthreads();
  #pragma unroll
  for (int it=0; it<4; it++){
    int f = tid + it*256;
    int r = f >> 4, c4 = (f & 15)*4;
    float4 v = make_float4(tile[c4+0][r], tile[c4+1][r], tile[c4+2][r], tile[c4+3][r]);
    *(float4*)(Tb + (size_t)(j0+r)*NN + i0 + c4) = v;
  }
}

// ---------------- sinkhorn passes ----------------
__global__ __launch_bounds__(256) void lse_rows_k(const float* __restrict__ Z,
                                                  const float* __restrict__ sub,
                                                  float* __restrict__ outv){
  __shared__ float redm[4], reds[4];
  int tid = threadIdx.x, wid = tid >> 6, lane = tid & 63;
  int row = blockIdx.x;
  int b = row >> 10;
  float4 z  = *(const float4*)(Z   + (size_t)row*NN + tid*4);
  float4 s4 = *(const float4*)(sub + (size_t)b*NN   + tid*4);
  float x0 = z.x - s4.x, x1 = z.y - s4.y, x2 = z.z - s4.z, x3 = z.w - s4.w;
  float m = fmaxf(fmaxf(x0,x1), fmaxf(x2,x3));
  m = wave_max(m);
  if (lane==0) redm[wid] = m;
  __syncthreads();
  float M = fmaxf(fmaxf(redm[0],redm[1]), fmaxf(redm[2],redm[3]));
  float s = expf(x0-M) + expf(x1-M) + expf(x2-M) + expf(x3-M);
  s = wave_sum(s);
  if (lane==0) reds[wid] = s;
  __syncthreads();
  if (tid==0) outv[row] = M + logf(reds[0]+reds[1]+reds[2]+reds[3]);
}

__global__ __launch_bounds__(256) void sumexp_rows_k(const float* __restrict__ Zt,
                                                     const float* __restrict__ Lv,
                                                     const float* __restrict__ Cv,
                                                     float* __restrict__ Tv){
  __shared__ float reds[4];
  int tid = threadIdx.x, wid = tid >> 6, lane = tid & 63;
  int row = blockIdx.x;
  int b = row >> 10;
  float sc = Cv[row];
  float4 z  = *(const float4*)(Zt + (size_t)row*NN + tid*4);
  float4 l4 = *(const float4*)(Lv + (size_t)b*NN   + tid*4);
  float s = expf(z.x - l4.x - sc) + expf(z.y - l4.y - sc)
          + expf(z.z - l4.z - sc) + expf(z.w - l4.w - sc);
  s = wave_sum(s);
  if (lane==0) reds[wid] = s;
  __syncthreads();
  if (tid==0) Tv[row] = reds[0]+reds[1]+reds[2]+reds[3];
}

__global__ __launch_bounds__(256) void writep_k(const float* __restrict__ Z,
                                                const float* __restrict__ Cv,
                                                const float* __restrict__ Lv,
                                                const float* __restrict__ Tv,
                                                float* __restrict__ P){
  int gid = blockIdx.x*256 + threadIdx.x;
  int row = gid >> 8;
  int j = (gid & 255)*4;
  int b = row >> 10;
  float4 z = ((const float4*)Z)[gid];
  float4 c = *(const float4*)(Cv + (size_t)b*NN + j);
  float4 t = *(const float4*)(Tv + (size_t)b*NN + j);
  float l = Lv[row];
  float4 o;
  o.x = expf(z.x - c.x - l) / t.x;
  o.y = expf(z.y - c.y - l) / t.y;
  o.z = expf(z.z - c.z - l) / t.z;
  o.w = expf(z.w - c.w - l) / t.w;
  ((float4*)P)[gid] = o;
}

// ---------------- host orchestration ----------------
extern "C" void kernel_launch(void* const* d_in, const int* in_sizes, int n_in,
                              void* d_out, int out_size, void* d_ws, size_t ws_size,
                              hipStream_t stream){
  const float* X    = (const float*)d_in[0];
  const float* adj  = (const float*)d_in[1];
  const float* w_in = (const float*)d_in[2];
  const float* b_in = (const float*)d_in[3];
  const float* cw1  = (const float*)d_in[4];
  const float* cb1  = (const float*)d_in[5];
  const float* cw2  = (const float*)d_in[6];
  const float* cb2  = (const float*)d_in[7];
  const float* ca   = (const float*)d_in[8];
  const float* m1w  = (const float*)d_in[9];
  const float* m1b  = (const float*)d_in[10];
  const float* m2w  = (const float*)d_in[11];
  const float* m2b  = (const float*)d_in[12];

  float* outp = (float*)d_out;
  float* Pout = outp;                              // [0,16M) floats
  float* Z0   = outp + (size_t)16*1024*1024;       // [16M,32M)

  // d_out scratch slots (16 MB each); all dead before the Z0/P writes that
  // overlap them (adjbf slots 6-7 overlap Z0 but die before mlp2; s2hl slot 0
  // overlaps P but dies before writep).
  const size_t SLOT = (size_t)4*1024*1024;
  float* s1 = outp + 0*SLOT;     // diffusion scratch (phase 1 only)
  float* s2 = outp + 1*SLOT;
  float* s3 = outp + 2*SLOT;
  float* s4 = outp + 3*SLOT;
  float* s5 = outp + 4*SLOT;
  float* s6 = outp + 5*SLOT;
  unsigned short* adjbf = (unsigned short*)(outp + 6*SLOT);   // 32 MB
  // mlp2 A pre-split lives in slot 0 (s1 dead by then; P written after mlp2)
  unsigned short* s2h = (unsigned short*)(outp + 0*SLOT);
  unsigned short* s2l = s2h + (size_t)MROWS*HD;

  float* ws     = (float*)d_ws;
  float* Zt     = ws;                                   // 16M floats (sinkhorn)
  float* hidden = ws;                                   // 12M floats (layers)
  float* dis    = ws + (size_t)12*1024*1024;
  float* rinv   = dis + 16384;
  unsigned short* bt = (unsigned short*)(rinv + 16384); // 8 MB
  // weights hi/lo at ws+15M floats (60 MB), inside the [56.4,64) MB gap
  unsigned short* wsp = (unsigned short*)(ws + (size_t)15*1024*1024);
  unsigned short* winh = wsp;               unsigned short* winl = winh + 32768;
  unsigned short* w1h  = winl + 32768;      unsigned short* w1l  = w1h + 131072;
  unsigned short* w2h  = w1l + 131072;      unsigned short* w2l  = w2h + 131072;
  unsigned short* m1h  = w2l + 131072;      unsigned short* m1l  = m1h + 196608;
  unsigned short* m2h  = m1l + 196608;      unsigned short* m2l  = m2h + 262144;
  float* Rv = ws + (size_t)16*1024*1024;
  float* Cv = Rv + 16384;
  float* Lv = Cv + 16384;
  float* Tv = Lv + 16384;

  dim3 blk(256);
  dim3 gEw(4096);
  dim3 gMM(2, 8, 16);             // MFMA adj gemm
  dim3 gCT(16, 4, 16);            // bconv_t
  dim3 gRow(MROWS);

  adj_prep_k<<<gEw, blk, 0, stream>>>(adj, dis, rinv, adjbf);
  // pre-split weights (hi/lo bf16), one-time
  split_flat_k<<<dim3(32),  blk, 0, stream>>>(w_in, winh, winl, 8192);
  split_flat_k<<<dim3(128), blk, 0, stream>>>(cw1,  w1h,  w1l,  32768);
  split_flat_k<<<dim3(128), blk, 0, stream>>>(cw2,  w2h,  w2l,  32768);
  split_flat_k<<<dim3(192), blk, 0, stream>>>(m1w,  m1h,  m1l,  49152);
  split_flat_k<<<dim3(256), blk, 0, stream>>>(m2w,  m2h,  m2l,  65536);

  // input projection: hidden[:, 0:256] = X @ w_in^T + b_in
  gemm_nt_mfma_k<<<dim3(2,128), dim3(512), 0, stream>>>(X, nullptr, nullptr, IND,
                                                        winh, winl, b_in, hidden, 768, IND, 0);

  for (int l=0; l<2; l++){
    const float* h_in = hidden + l*HD;       // ld 768
    unsigned short* wl1h = w1h + (size_t)l*65536;
    unsigned short* wl1l = w1l + (size_t)l*65536;
    unsigned short* wl2h = w2h + (size_t)l*65536;
    unsigned short* wl2l = w2l + (size_t)l*65536;
    const float* b1 = cb1 + (size_t)l*HD;
    const float* b2 = cb2 + (size_t)l*HD;
    const float* a2 = ca  + (size_t)l*2*HD + HD;   // x-part cancels in channel softmax

    // C0 = leaky(A_hat h): bt = bf16(dis.*h), epilogue re-applies dis
    bconv_t_k<<<gCT, blk, 0, stream>>>(h_in, 768, dis, bt);
    gemm_nn_mfma_k<<<gMM, dim3(512), 0, stream>>>(adjbf, bt, h_in, 768, dis, s2, 2);
    // t1 = P h
    bconv_t_k<<<gCT, blk, 0, stream>>>(h_in, 768, nullptr, bt);
    gemm_nn_mfma_k<<<gMM, dim3(512), 0, stream>>>(adjbf, bt, h_in, 768, rinv, s1, 1);
    sub_abs_k<<<gEw, blk, 0, stream>>>(h_in, 768, s1, HD, s3);             // S0
    // t2 = P t1
    bconv_t_k<<<gCT, blk, 0, stream>>>(s1, HD, nullptr, bt);
    gemm_nn_mfma_k<<<gMM, dim3(512), 0, stream>>>(adjbf, bt, s1, HD, rinv, s4, 1);
    sub_abs_k<<<gEw, blk, 0, stream>>>(s1, HD, s4, HD, s5);                // S1
    // t3, t4
    bconv_t_k<<<gCT, blk, 0, stream>>>(s4, HD, nullptr, bt);
    gemm_nn_mfma_k<<<gMM, dim3(512), 0, stream>>>(adjbf, bt, s4, HD, rinv, s1, 1);
    bconv_t_k<<<gCT, blk, 0, stream>>>(s1, HD, nullptr, bt);
    gemm_nn_mfma_k<<<gMM, dim3(512), 0, stream>>>(adjbf, bt, s1, HD, rinv, s6, 1);
    sub_abs_k<<<gEw, blk, 0, stream>>>(s4, HD, s6, HD, s1);                // S2
    // attention combine -> h'
    attn_k<<<gEw, blk, 0, stream>>>(s2, s3, s5, s1, a2, s4);
    // two linears (split-bf16 MFMA, W pre-split)
    gemm_nt_mfma_k<<<dim3(2,128), dim3(512), 0, stream>>>(s4, nullptr, nullptr, HD,
                                                          wl1h, wl1l, b1, s1, HD, HD, 1);
    gemm_nt_mfma_k<<<dim3(2,128), dim3(512), 0, stream>>>(s1, nullptr, nullptr, HD,
                                                          wl2h, wl2l, b2, hidden + (l+1)*HD, 768, HD, 1);
  }

  // MLP head
  gemm_nt_mfma_k<<<dim3(2,128), dim3(512), 0, stream>>>(hidden, nullptr, nullptr, 768,
                                                        m1h, m1l, m1b, s2, HD, 768, 1);
  split_flat_k<<<dim3(4096), blk, 0, stream>>>(s2, s2h, s2l, 1048576);
  gemm_nt_mfma_k<<<dim3(8,128), dim3(512), 0, stream>>>(nullptr, s2h, s2l, HD,
                                                        m2h, m2l, m2b, Z0, OUTD, HD, 2);

  // Sinkhorn: Z_t = Z0 - R_i - C_j (rank-1 log-space; Z0 read-only)
  transpose_k<<<dim3(16,16,16), blk, 0, stream>>>(Z0, Zt);
  hipMemsetAsync(Cv, 0, MROWS*sizeof(float), stream);
  for (int t=0; t<20; t++){
    lse_rows_k<<<gRow, blk, 0, stream>>>(Z0, Cv, Rv);
    lse_rows_k<<<gRow, blk, 0, stream>>>(Zt, Rv, Cv);
  }
  lse_rows_k<<<gRow, blk, 0, stream>>>(Z0, Cv, Lv);
  sumexp_rows_k<<<gRow, blk, 0, stream>>>(Zt, Lv, Cv, Tv);
  writep_k<<<gRow, blk, 0, stream>>>(Z0, Cv, Lv, Tv, Pout);
}